// Round 1
// baseline (755.160 us; speedup 1.0000x reference)
//
#include <hip/hip_runtime.h>
#include <math.h>

#define HCH   128
#define NMODE 32
#define BB    8
#define LLEN  8192
#define LC    256
#define CCH   (LLEN / LC)      // 32 chunks per row
#define ROWS  (BB * HCH)       // 1024

// complex state update: S = w*S + xv   (Si uses old Sr)
#define UPD(xv) { float _t = fmaf(-wi, Si, (xv)); float _sr = fmaf(wr, Sr, _t); \
                  Si = fmaf(wi, Sr, wr * Si); Sr = _sr; }

// sum over each 32-lane half
#define RED(v) { v += __shfl_xor(v, 1);  v += __shfl_xor(v, 2);  v += __shfl_xor(v, 4); \
                 v += __shfl_xor(v, 8);  v += __shfl_xor(v, 16); }

// ---------------- K1: per-(h,n) parameters + zero BN stats ----------------
__global__ void k_setup(const float* __restrict__ C_re, const float* __restrict__ C_im,
                        const float* __restrict__ logA, const float* __restrict__ Aim,
                        const float* __restrict__ logdt,
                        float* __restrict__ P, float* __restrict__ stats) {
    int i = blockIdx.x * 256 + threadIdx.x;
    if (blockIdx.x == 0 && threadIdx.x < 2 * HCH) stats[threadIdx.x] = 0.f;
    if (i >= HCH * NMODE) return;
    int h = i / NMODE;
    float ar = expf(logA[i]);
    float ai = Aim[i];
    float dt = expf(logdt[h]);
    float dre = -ar * dt, dim = ai * dt;
    float er = expf(dre);
    float wr = er * cosf(dim), wi = er * sinf(dim);
    float eL = expf(dre * (float)LC);
    float wLr = eL * cosf(dim * (float)LC), wLi = eL * sinf(dim * (float)LC);
    // K = (w-1)/A, A = -ar + i*ai  ->  (w-1)*conj(A)/|A|^2
    float den  = ar * ar + ai * ai;
    float numr = -(wr - 1.f) * ar + wi * ai;
    float numi = -wi * ar - (wr - 1.f) * ai;
    float Kr = numr / den, Ki = numi / den;
    float c0r = C_re[i],             c0i = C_im[i];
    float c1r = C_re[HCH*NMODE + i], c1i = C_im[HCH*NMODE + i];
    P[0*4096 + i] = wr;   P[1*4096 + i] = wi;
    P[2*4096 + i] = wLr;  P[3*4096 + i] = wLi;
    P[4*4096 + i] = 2.f * (c0r * Kr - c0i * Ki);   // G0 (2x folded)
    P[5*4096 + i] = 2.f * (c0r * Ki + c0i * Kr);
    P[6*4096 + i] = 2.f * (c1r * Kr - c1i * Ki);   // G1
    P[7*4096 + i] = 2.f * (c1r * Ki + c1i * Kr);
}

// ---------------- K2a: per-chunk local states (both directions) ----------------
// wave = (row, chunk); lane = d*32 + n. causal scans ascending, anti descending.
__global__ __launch_bounds__(256) void k_states(const float* __restrict__ x,
                                                const float* __restrict__ P,
                                                float* __restrict__ states) {
    int wid  = (blockIdx.x << 2) + (threadIdx.x >> 6);
    int lane = threadIdx.x & 63;
    int c = wid & (CCH - 1);
    int row = wid >> 5;               // CCH = 32
    int h = row & (HCH - 1);
    int d = lane >> 5, n = lane & 31;
    int pi = h * NMODE + n;
    float wr = P[pi], wi = P[4096 + pi];
    const float* xr = x + (size_t)row * LLEN + c * LC;
    float Sr = 0.f, Si = 0.f;
    for (int j4 = 0; j4 < LC; j4 += 4) {
        int off = d ? (LC - 4 - j4) : j4;
        float4 v = *(const float4*)(xr + off);
        float a0 = d ? v.w : v.x;
        float a1 = d ? v.z : v.y;
        float a2 = d ? v.y : v.z;
        float a3 = d ? v.x : v.w;
        UPD(a0); UPD(a1); UPD(a2); UPD(a3);
    }
    size_t sidx = ((((size_t)row * 2 + d) * NMODE + n) * CCH + c) * 2;
    states[sidx] = Sr; states[sidx + 1] = Si;
}

// ---------------- K2b: carry propagation across chunks ----------------
// thread = (row, d, n); sequential over C=32 chunks.
__global__ void k_carries(const float* __restrict__ states, const float* __restrict__ P,
                          float* __restrict__ carries) {
    int i = blockIdx.x * 256 + threadIdx.x;   // over ROWS*2*NMODE = 65536
    int n = i & 31; int d = (i >> 5) & 1; int row = i >> 6;
    int h = row & (HCH - 1);
    int pi = h * NMODE + n;
    float wLr = P[2*4096 + pi], wLi = P[3*4096 + pi];
    const float* S = states + (size_t)i * CCH * 2;
    float* Ca = carries + (size_t)i * CCH * 2;
    float cr = 0.f, ci = 0.f;
    if (d == 0) {
        for (int c = 0; c < CCH; c++) {        // carry[c] = state entering chunk c
            Ca[2*c] = cr; Ca[2*c + 1] = ci;
            float nr = fmaf(wLr, cr, -wLi * ci) + S[2*c];
            float ni = fmaf(wLi, cr,  wLr * ci) + S[2*c + 1];
            cr = nr; ci = ni;
        }
    } else {
        for (int c = CCH - 1; c >= 0; c--) {   // carryU[c] = T at end of chunk c
            Ca[2*c] = cr; Ca[2*c + 1] = ci;
            float nr = fmaf(wLr, cr, -wLi * ci) + S[2*c];
            float ni = fmaf(wLi, cr,  wLr * ci) + S[2*c + 1];
            cr = nr; ci = ni;
        }
    }
}

// ---------------- K2c: carry-initialized in-chunk scan -> y_conv ----------------
// wave = (row, chunk). lanes 0-31 causal (t ascending), 32-63 anticausal (t descending).
__global__ __launch_bounds__(256) void k_scanout(const float* __restrict__ x,
                                                 const float* __restrict__ P,
                                                 const float* __restrict__ carries,
                                                 float* __restrict__ yconv) {
    __shared__ __align__(16) float ylds[4][LC];
    int wslot = threadIdx.x >> 6;
    int lane  = threadIdx.x & 63;
    int wid = (blockIdx.x << 2) + wslot;
    int c = wid & (CCH - 1);
    int row = wid >> 5;
    int h = row & (HCH - 1);
    int d = lane >> 5, n = lane & 31;
    int pi = h * NMODE + n;
    float wr = P[pi], wi = P[4096 + pi];
    float gr = P[(4 + 2*d) * 4096 + pi];
    float gi = P[(5 + 2*d) * 4096 + pi];
    size_t cidx = ((((size_t)row * 2 + d) * NMODE + n) * CCH + c) * 2;
    float Sr = carries[cidx], Si = carries[cidx + 1];
    // zero this wave's LDS row (64 lanes x 4 floats = 256)
    ((float4*)&ylds[wslot][0])[lane] = make_float4(0.f, 0.f, 0.f, 0.f);
    const float* xr = x + (size_t)row * LLEN + c * LC;
    bool low = (d == 0);
    // j = 0: causal updates with x[t0]; anticausal emits carryU directly (T(t1-1))
    if (low) { float xv = xr[0]; UPD(xv); }
    {
        float v = fmaf(gr, Sr, -gi * Si);
        RED(v);
        if ((lane & 31) == 0) atomicAdd(&ylds[wslot][low ? 0 : (LC - 1)], v);
    }
    int xo  = low ? 1 : (LC - 1);
    int yo  = low ? 1 : (LC - 2);
    int stp = low ? 1 : -1;
    for (int j = 1; j < LC; j++) {
        float xv = xr[xo];
        UPD(xv);
        float v = fmaf(gr, Sr, -gi * Si);
        RED(v);
        if ((lane & 31) == 0) atomicAdd(&ylds[wslot][yo], v);
        xo += stp; yo += stp;
    }
    __syncthreads();
    float4 o4 = ((const float4*)&ylds[wslot][0])[lane];
    *(float4*)(yconv + (size_t)row * LLEN + c * LC + lane * 4) = o4;
}

// ---------------- K3: fused skip+GELU + 128x128 pointwise conv ----------------
__global__ __launch_bounds__(256) void k_pointwise(const float* __restrict__ yconv,
                                                   const float* __restrict__ x,
                                                   const float* __restrict__ W,
                                                   const float* __restrict__ D,
                                                   float* __restrict__ z) {
    __shared__ float Wt[32][132];   // [h][o], padded
    __shared__ float Yt[32][68];    // [h][l], padded (16B-aligned rows)
    int b  = blockIdx.x >> 7;
    int l0 = (blockIdx.x & 127) << 6;
    int tid = threadIdx.x;
    int to4 = (tid & 31) << 2;      // owns o = to4..to4+3
    int tl  = tid >> 5;             // owns l = tl*8..tl*8+7
    float acc[4][8];
    #pragma unroll
    for (int a = 0; a < 4; a++)
        #pragma unroll
        for (int j = 0; j < 8; j++) acc[a][j] = 0.f;

    for (int ht = 0; ht < 4; ht++) {
        int hbase = ht * 32;
        __syncthreads();
        for (int i = tid; i < 4096; i += 256) {          // stage W tile
            int o = i >> 5, hh = i & 31;
            Wt[hh][o] = W[o * HCH + hbase + hh];
        }
        for (int i = tid; i < 2048; i += 256) {          // stage activated y tile
            int hh = i >> 6, l = i & 63;
            int hcur = hbase + hh;
            size_t gi = (size_t)(b * HCH + hcur) * LLEN + l0 + l;
            float yv = yconv[gi] + D[hcur] * x[gi];
            Yt[hh][l] = 0.5f * yv * (1.f + erff(yv * 0.70710678118654752f));
        }
        __syncthreads();
        #pragma unroll 8
        for (int hh = 0; hh < 32; hh++) {
            float4 wv = *(const float4*)&Wt[hh][to4];
            float4 ya = *(const float4*)&Yt[hh][tl * 8];
            float4 yb = *(const float4*)&Yt[hh][tl * 8 + 4];
            float wv4[4] = {wv.x, wv.y, wv.z, wv.w};
            float yv8[8] = {ya.x, ya.y, ya.z, ya.w, yb.x, yb.y, yb.z, yb.w};
            #pragma unroll
            for (int a = 0; a < 4; a++)
                #pragma unroll
                for (int j = 0; j < 8; j++)
                    acc[a][j] = fmaf(wv4[a], yv8[j], acc[a][j]);
        }
    }
    #pragma unroll
    for (int a = 0; a < 4; a++) {
        int o = to4 + a;
        size_t go = (size_t)(b * HCH + o) * LLEN + l0 + tl * 8;
        float4 s0 = {acc[a][0], acc[a][1], acc[a][2], acc[a][3]};
        float4 s1 = {acc[a][4], acc[a][5], acc[a][6], acc[a][7]};
        *(float4*)(z + go)     = s0;
        *(float4*)(z + go + 4) = s1;
    }
}

// ---------------- K4a: BN statistics (sum, sumsq per channel) ----------------
__global__ __launch_bounds__(256) void k_stats(const float* __restrict__ z,
                                               float* __restrict__ stats) {
    int row = blockIdx.x;                 // (b*H + o)
    int o = row & (HCH - 1);
    const float4* zr = (const float4*)(z + (size_t)row * LLEN);
    float s = 0.f, q = 0.f;
    for (int i = threadIdx.x; i < LLEN / 4; i += 256) {
        float4 v = zr[i];
        s += v.x + v.y + v.z + v.w;
        q += v.x*v.x + v.y*v.y + v.z*v.z + v.w*v.w;
    }
    for (int m = 1; m <= 32; m <<= 1) { s += __shfl_xor(s, m); q += __shfl_xor(q, m); }
    __shared__ float ls[4], lq[4];
    int w = threadIdx.x >> 6;
    if ((threadIdx.x & 63) == 0) { ls[w] = s; lq[w] = q; }
    __syncthreads();
    if (threadIdx.x == 0) {
        s = ls[0] + ls[1] + ls[2] + ls[3];
        q = lq[0] + lq[1] + lq[2] + lq[3];
        atomicAdd(&stats[o], s);
        atomicAdd(&stats[HCH + o], q);
    }
}

// ---------------- K4b: BN normalize + ELU + residual ----------------
__global__ __launch_bounds__(256) void k_final(const float* __restrict__ z,
                                               const float* __restrict__ x,
                                               const float* __restrict__ stats,
                                               const float* __restrict__ gamma,
                                               const float* __restrict__ beta,
                                               float* __restrict__ out) {
    size_t i4 = (size_t)blockIdx.x * 256 + threadIdx.x;
    if (i4 >= (size_t)BB * HCH * LLEN / 4) return;
    size_t flat = i4 * 4;
    int o = (int)((flat / LLEN) & (HCH - 1));
    const float inv_cnt = 1.f / (float)(BB * LLEN);
    float m   = stats[o] * inv_cnt;
    float var = stats[HCH + o] * inv_cnt - m * m;
    float rs  = rsqrtf(var + 1e-5f);
    float ga  = gamma[o] * rs;
    float bt  = beta[o] - m * ga;
    float4 zv = ((const float4*)z)[i4];
    float4 xv = ((const float4*)x)[i4];
    float4 r;
    { float t = fmaf(zv.x, ga, bt); float e = t > 0.f ? t : expm1f(t); r.x = e + xv.x; }
    { float t = fmaf(zv.y, ga, bt); float e = t > 0.f ? t : expm1f(t); r.y = e + xv.y; }
    { float t = fmaf(zv.z, ga, bt); float e = t > 0.f ? t : expm1f(t); r.z = e + xv.z; }
    { float t = fmaf(zv.w, ga, bt); float e = t > 0.f ? t : expm1f(t); r.w = e + xv.w; }
    ((float4*)out)[i4] = r;
}

extern "C" void kernel_launch(void* const* d_in, const int* in_sizes, int n_in,
                              void* d_out, int out_size, void* d_ws, size_t ws_size,
                              hipStream_t stream) {
    const float* x     = (const float*)d_in[0];
    const float* C_re  = (const float*)d_in[1];
    const float* C_im  = (const float*)d_in[2];
    const float* logA  = (const float*)d_in[3];
    const float* Aim   = (const float*)d_in[4];
    const float* logdt = (const float*)d_in[5];
    const float* D     = (const float*)d_in[6];
    const float* W     = (const float*)d_in[7];
    const float* gamma = (const float*)d_in[8];
    const float* beta  = (const float*)d_in[9];

    float* ws      = (float*)d_ws;
    float* yconv   = ws;                       // 8388608 floats (32 MB)
    float* zbuf    = ws + 8388608;             // 8388608 floats (32 MB)
    float* states  = zbuf;                     // aliased: dead before z written
    float* carries = zbuf + 4194304;           // aliased: dead before z written
    float* P       = ws + 16777216;            // 8 * 4096 floats
    float* stats   = P + 8 * 4096;             // 256 floats
    float* out     = (float*)d_out;

    k_setup   <<<16,   256, 0, stream>>>(C_re, C_im, logA, Aim, logdt, P, stats);
    k_states  <<<8192, 256, 0, stream>>>(x, P, states);
    k_carries <<<256,  256, 0, stream>>>(states, P, carries);
    k_scanout <<<8192, 256, 0, stream>>>(x, P, carries, yconv);
    k_pointwise<<<1024,256, 0, stream>>>(yconv, x, W, D, zbuf);
    k_stats   <<<1024, 256, 0, stream>>>(zbuf, stats);
    k_final   <<<8192, 256, 0, stream>>>(zbuf, x, stats, gamma, beta, out);
}

// Round 3
// 395.198 us; speedup vs baseline: 1.9108x; 1.9108x over previous
//
#include <hip/hip_runtime.h>
#include <math.h>

#define HCH   128
#define NMODE 32
#define BB    8
#define LLEN  8192
#define LC    256
#define CCH   (LLEN / LC)      // 32 chunks per row
#define ROWS  (BB * HCH)       // 1024

// complex state update: S = w*S + xv   (Si uses old Sr)
#define UPD(xv) { float _t = fmaf(-wi, Si, (xv)); float _sr = fmaf(wr, Sr, _t); \
                  Si = fmaf(wi, Sr, wr * Si); Sr = _sr; }

// ---------------- K1: per-(h,n) parameters + zero BN stats ----------------
__global__ void k_setup(const float* __restrict__ C_re, const float* __restrict__ C_im,
                        const float* __restrict__ logA, const float* __restrict__ Aim,
                        const float* __restrict__ logdt,
                        float* __restrict__ P, float* __restrict__ stats) {
    int i = blockIdx.x * 256 + threadIdx.x;
    if (blockIdx.x == 0 && threadIdx.x < 2 * HCH) stats[threadIdx.x] = 0.f;
    if (i >= HCH * NMODE) return;
    int h = i / NMODE;
    float ar = expf(logA[i]);
    float ai = Aim[i];
    float dt = expf(logdt[h]);
    float dre = -ar * dt, dim = ai * dt;
    float er = expf(dre);
    float wr = er * cosf(dim), wi = er * sinf(dim);
    float eL = expf(dre * (float)LC);
    float wLr = eL * cosf(dim * (float)LC), wLi = eL * sinf(dim * (float)LC);
    // K = (w-1)/A, A = -ar + i*ai  ->  (w-1)*conj(A)/|A|^2
    float den  = ar * ar + ai * ai;
    float numr = -(wr - 1.f) * ar + wi * ai;
    float numi = -wi * ar - (wr - 1.f) * ai;
    float Kr = numr / den, Ki = numi / den;
    float c0r = C_re[i],             c0i = C_im[i];
    float c1r = C_re[HCH*NMODE + i], c1i = C_im[HCH*NMODE + i];
    P[0*4096 + i] = wr;   P[1*4096 + i] = wi;
    P[2*4096 + i] = wLr;  P[3*4096 + i] = wLi;
    P[4*4096 + i] = 2.f * (c0r * Kr - c0i * Ki);   // G0 (2x folded)
    P[5*4096 + i] = 2.f * (c0r * Ki + c0i * Kr);
    P[6*4096 + i] = 2.f * (c1r * Kr - c1i * Ki);   // G1
    P[7*4096 + i] = 2.f * (c1r * Ki + c1i * Kr);
}

// ---------------- K2a: per-chunk local states (both directions) ----------------
// wave = (row, chunk); lane = d*32 + n. causal scans ascending, anti descending.
__global__ __launch_bounds__(256) void k_states(const float* __restrict__ x,
                                                const float* __restrict__ P,
                                                float* __restrict__ states) {
    int wid  = (blockIdx.x << 2) + (threadIdx.x >> 6);
    int lane = threadIdx.x & 63;
    int c = wid & (CCH - 1);
    int row = wid >> 5;               // CCH = 32
    int h = row & (HCH - 1);
    int d = lane >> 5, n = lane & 31;
    int pi = h * NMODE + n;
    float wr = P[pi], wi = P[4096 + pi];
    const float* xr = x + (size_t)row * LLEN + c * LC;
    float Sr = 0.f, Si = 0.f;
    for (int j4 = 0; j4 < LC; j4 += 4) {
        int off = d ? (LC - 4 - j4) : j4;
        float4 v = *(const float4*)(xr + off);
        float a0 = d ? v.w : v.x;
        float a1 = d ? v.z : v.y;
        float a2 = d ? v.y : v.z;
        float a3 = d ? v.x : v.w;
        UPD(a0); UPD(a1); UPD(a2); UPD(a3);
    }
    size_t sidx = ((((size_t)row * 2 + d) * NMODE + n) * CCH + c) * 2;
    states[sidx] = Sr; states[sidx + 1] = Si;
}

// ---------------- K2b: carry propagation across chunks ----------------
// thread = (row, d, n); sequential over C=32 chunks.
// Output layout: carries[((row*2+d)*CCH + c)*64 + 2n {,+1}]  (modes contiguous per chunk)
__global__ void k_carries(const float* __restrict__ states, const float* __restrict__ P,
                          float* __restrict__ carries) {
    int i = blockIdx.x * 256 + threadIdx.x;   // over ROWS*2*NMODE = 65536
    int n = i & 31; int d = (i >> 5) & 1; int row = i >> 6;
    int h = row & (HCH - 1);
    int pi = h * NMODE + n;
    float wLr = P[2*4096 + pi], wLi = P[3*4096 + pi];
    const float* S = states + (size_t)i * CCH * 2;
    float* Ca = carries + ((size_t)row * 2 + d) * CCH * 64 + 2 * n;
    float cr = 0.f, ci = 0.f;
    if (d == 0) {
        for (int c = 0; c < CCH; c++) {        // carry[c] = state entering chunk c
            Ca[(size_t)c * 64] = cr; Ca[(size_t)c * 64 + 1] = ci;
            float nr = fmaf(wLr, cr, -wLi * ci) + S[2*c];
            float ni = fmaf(wLi, cr,  wLr * ci) + S[2*c + 1];
            cr = nr; ci = ni;
        }
    } else {
        for (int c = CCH - 1; c >= 0; c--) {   // carryU[c] = T at end (local t=255) of chunk c
            Ca[(size_t)c * 64] = cr; Ca[(size_t)c * 64 + 1] = ci;
            float nr = fmaf(wLr, cr, -wLi * ci) + S[2*c];
            float ni = fmaf(wLi, cr,  wLr * ci) + S[2*c + 1];
            cr = nr; ci = ni;
        }
    }
}

// ---------------- K2c: carry-initialized in-chunk scan -> y_conv ----------------
// block = (row, half): 4 waves cover 16 chunks x 2 dirs.
// lane group g = lane>>3 (8 lanes, 4 modes each): d = g&1, chunk = wslot*4 + (g>>1).
// Unified emit: v = e*x[t] + Re(sum H*S_pre); then S = w*S + x[t]; t += stp.
//   causal: H = G*w, e = sum Re(G)  (emit-after-update folded into coefficients)
//   anti:   H = G,   e = 0          (emit-before-update, consumes x[t] at emit t)
__global__ __launch_bounds__(256, 6) void k_scanout(const float* __restrict__ x,
                                                    const float* __restrict__ P,
                                                    const float* __restrict__ carries,
                                                    float* __restrict__ yconv) {
    __shared__ float ylds[16 * 257];           // [c_local][t], +1 pad vs 256
    int tid   = threadIdx.x;
    int wslot = tid >> 6;
    int lane  = tid & 63;
    int g  = lane >> 3;
    int lp = lane & 7;
    int row  = blockIdx.x >> 1;
    int half = blockIdx.x & 1;
    int h = row & (HCH - 1);
    int d = g & 1;
    int c_local = (wslot << 2) + (g >> 1);     // 0..15
    int c = (half << 4) + c_local;             // 0..31
    int n0 = lp << 2;
    int pi = h * NMODE + n0;

    float4 w_r = *(const float4*)&P[pi];
    float4 w_i = *(const float4*)&P[4096 + pi];
    float4 g_r = *(const float4*)&P[(4 + 2*d) * 4096 + pi];
    float4 g_i = *(const float4*)&P[(5 + 2*d) * 4096 + pi];
    float wr[4] = {w_r.x, w_r.y, w_r.z, w_r.w};
    float wi[4] = {w_i.x, w_i.y, w_i.z, w_i.w};
    float gr[4] = {g_r.x, g_r.y, g_r.z, g_r.w};
    float gi[4] = {g_i.x, g_i.y, g_i.z, g_i.w};
    float Hr[4], Hi[4], e;
    if (d == 0) {
        #pragma unroll
        for (int k = 0; k < 4; k++) {
            Hr[k] = gr[k] * wr[k] - gi[k] * wi[k];
            Hi[k] = gr[k] * wi[k] + gi[k] * wr[k];
        }
        e = gr[0] + gr[1] + gr[2] + gr[3];
    } else {
        #pragma unroll
        for (int k = 0; k < 4; k++) { Hr[k] = gr[k]; Hi[k] = gi[k]; }
        e = 0.f;
    }

    size_t cb = (((size_t)row * 2 + d) * CCH + c) * 64 + (n0 << 1);
    float4 ca = *(const float4*)&carries[cb];
    float4 cbv = *(const float4*)&carries[cb + 4];
    float Sr[4] = {ca.x, ca.z, cbv.x, cbv.z};
    float Si[4] = {ca.y, ca.w, cbv.y, cbv.w};

    for (int i = tid; i < 16 * 257; i += 256) ylds[i] = 0.f;
    __syncthreads();

    const float* xr = x + (size_t)row * LLEN + ((size_t)c << 8);
    int stp = 1 - 2 * d;
    int t = d ? 255 : 0;
    int ybase = c_local * 257;

    for (int j = 0; j < 256; j += 4) {
        int xoff = d ? (252 - j) : j;
        float4 xv4 = *(const float4*)(xr + xoff);
        float xs0 = d ? xv4.w : xv4.x;
        float xs1 = d ? xv4.z : xv4.y;
        float xs2 = d ? xv4.y : xv4.z;
        float xs3 = d ? xv4.x : xv4.w;
        float xs[4] = {xs0, xs1, xs2, xs3};
        #pragma unroll
        for (int q = 0; q < 4; q++) {
            float xv = xs[q];
            float v = e * xv;
            #pragma unroll
            for (int k = 0; k < 4; k++)
                v = fmaf(Hr[k], Sr[k], fmaf(-Hi[k], Si[k], v));
            v += __shfl_xor(v, 1);
            v += __shfl_xor(v, 2);
            v += __shfl_xor(v, 4);
            if (lp == 0) atomicAdd(&ylds[ybase + t], v);
            #pragma unroll
            for (int k = 0; k < 4; k++) {
                float t0  = fmaf(-wi[k], Si[k], xv);
                float nsr = fmaf(wr[k], Sr[k], t0);
                Si[k] = fmaf(wi[k], Sr[k], wr[k] * Si[k]);
                Sr[k] = nsr;
            }
            t += stp;
        }
    }
    __syncthreads();
    // copy out: 16 chunks x 256 = 4096 floats; 256 threads x 4 floats x 4 passes
    float* yo = yconv + (size_t)row * LLEN + ((size_t)half << 12);
    #pragma unroll
    for (int base = 0; base < 4096; base += 1024) {
        int idx = base + (tid << 2);
        int cl  = idx >> 8;
        int tl0 = idx & 255;
        float4 o4;
        o4.x = ylds[cl * 257 + tl0];
        o4.y = ylds[cl * 257 + tl0 + 1];
        o4.z = ylds[cl * 257 + tl0 + 2];
        o4.w = ylds[cl * 257 + tl0 + 3];
        *(float4*)(yo + idx) = o4;
    }
}

// ---------------- K3: fused skip+GELU + 128x128 pointwise conv ----------------
__global__ __launch_bounds__(256) void k_pointwise(const float* __restrict__ yconv,
                                                   const float* __restrict__ x,
                                                   const float* __restrict__ W,
                                                   const float* __restrict__ D,
                                                   float* __restrict__ z) {
    __shared__ float Wt[32][132];   // [h][o], padded
    __shared__ float Yt[32][68];    // [h][l], padded (16B-aligned rows)
    int b  = blockIdx.x >> 7;
    int l0 = (blockIdx.x & 127) << 6;
    int tid = threadIdx.x;
    int to4 = (tid & 31) << 2;      // owns o = to4..to4+3
    int tl  = tid >> 5;             // owns l = tl*8..tl*8+7
    float acc[4][8];
    #pragma unroll
    for (int a = 0; a < 4; a++)
        #pragma unroll
        for (int j = 0; j < 8; j++) acc[a][j] = 0.f;

    for (int ht = 0; ht < 4; ht++) {
        int hbase = ht * 32;
        __syncthreads();
        for (int i = tid; i < 4096; i += 256) {          // stage W tile
            int o = i >> 5, hh = i & 31;
            Wt[hh][o] = W[o * HCH + hbase + hh];
        }
        for (int i = tid; i < 2048; i += 256) {          // stage activated y tile
            int hh = i >> 6, l = i & 63;
            int hcur = hbase + hh;
            size_t gi = (size_t)(b * HCH + hcur) * LLEN + l0 + l;
            float yv = yconv[gi] + D[hcur] * x[gi];
            Yt[hh][l] = 0.5f * yv * (1.f + erff(yv * 0.70710678118654752f));
        }
        __syncthreads();
        #pragma unroll 8
        for (int hh = 0; hh < 32; hh++) {
            float4 wv = *(const float4*)&Wt[hh][to4];
            float4 ya = *(const float4*)&Yt[hh][tl * 8];
            float4 yb = *(const float4*)&Yt[hh][tl * 8 + 4];
            float wv4[4] = {wv.x, wv.y, wv.z, wv.w};
            float yv8[8] = {ya.x, ya.y, ya.z, ya.w, yb.x, yb.y, yb.z, yb.w};
            #pragma unroll
            for (int a = 0; a < 4; a++)
                #pragma unroll
                for (int j = 0; j < 8; j++)
                    acc[a][j] = fmaf(wv4[a], yv8[j], acc[a][j]);
        }
    }
    #pragma unroll
    for (int a = 0; a < 4; a++) {
        int o = to4 + a;
        size_t go = (size_t)(b * HCH + o) * LLEN + l0 + tl * 8;
        float4 s0 = {acc[a][0], acc[a][1], acc[a][2], acc[a][3]};
        float4 s1 = {acc[a][4], acc[a][5], acc[a][6], acc[a][7]};
        *(float4*)(z + go)     = s0;
        *(float4*)(z + go + 4) = s1;
    }
}

// ---------------- K4a: BN statistics (sum, sumsq per channel) ----------------
__global__ __launch_bounds__(256) void k_stats(const float* __restrict__ z,
                                               float* __restrict__ stats) {
    int row = blockIdx.x;                 // (b*H + o)
    int o = row & (HCH - 1);
    const float4* zr = (const float4*)(z + (size_t)row * LLEN);
    float s = 0.f, q = 0.f;
    for (int i = threadIdx.x; i < LLEN / 4; i += 256) {
        float4 v = zr[i];
        s += v.x + v.y + v.z + v.w;
        q += v.x*v.x + v.y*v.y + v.z*v.z + v.w*v.w;
    }
    for (int m = 1; m <= 32; m <<= 1) { s += __shfl_xor(s, m); q += __shfl_xor(q, m); }
    __shared__ float ls[4], lq[4];
    int w = threadIdx.x >> 6;
    if ((threadIdx.x & 63) == 0) { ls[w] = s; lq[w] = q; }
    __syncthreads();
    if (threadIdx.x == 0) {
        s = ls[0] + ls[1] + ls[2] + ls[3];
        q = lq[0] + lq[1] + lq[2] + lq[3];
        atomicAdd(&stats[o], s);
        atomicAdd(&stats[HCH + o], q);
    }
}

// ---------------- K4b: BN normalize + ELU + residual ----------------
__global__ __launch_bounds__(256) void k_final(const float* __restrict__ z,
                                               const float* __restrict__ x,
                                               const float* __restrict__ stats,
                                               const float* __restrict__ gamma,
                                               const float* __restrict__ beta,
                                               float* __restrict__ out) {
    size_t i4 = (size_t)blockIdx.x * 256 + threadIdx.x;
    if (i4 >= (size_t)BB * HCH * LLEN / 4) return;
    size_t flat = i4 * 4;
    int o = (int)((flat / LLEN) & (HCH - 1));
    const float inv_cnt = 1.f / (float)(BB * LLEN);
    float m   = stats[o] * inv_cnt;
    float var = stats[HCH + o] * inv_cnt - m * m;
    float rs  = rsqrtf(var + 1e-5f);
    float ga  = gamma[o] * rs;
    float bt  = beta[o] - m * ga;
    float4 zv = ((const float4*)z)[i4];
    float4 xv = ((const float4*)x)[i4];
    float4 r;
    { float t = fmaf(zv.x, ga, bt); float e = t > 0.f ? t : expm1f(t); r.x = e + xv.x; }
    { float t = fmaf(zv.y, ga, bt); float e = t > 0.f ? t : expm1f(t); r.y = e + xv.y; }
    { float t = fmaf(zv.z, ga, bt); float e = t > 0.f ? t : expm1f(t); r.z = e + xv.z; }
    { float t = fmaf(zv.w, ga, bt); float e = t > 0.f ? t : expm1f(t); r.w = e + xv.w; }
    ((float4*)out)[i4] = r;
}

extern "C" void kernel_launch(void* const* d_in, const int* in_sizes, int n_in,
                              void* d_out, int out_size, void* d_ws, size_t ws_size,
                              hipStream_t stream) {
    const float* x     = (const float*)d_in[0];
    const float* C_re  = (const float*)d_in[1];
    const float* C_im  = (const float*)d_in[2];
    const float* logA  = (const float*)d_in[3];
    const float* Aim   = (const float*)d_in[4];
    const float* logdt = (const float*)d_in[5];
    const float* D     = (const float*)d_in[6];
    const float* W     = (const float*)d_in[7];
    const float* gamma = (const float*)d_in[8];
    const float* beta  = (const float*)d_in[9];

    float* ws      = (float*)d_ws;
    float* yconv   = ws;                       // 8388608 floats (32 MB)
    float* zbuf    = ws + 8388608;             // 8388608 floats (32 MB)
    float* states  = zbuf;                     // aliased: dead before z written
    float* carries = zbuf + 4194304;           // aliased: dead before z written
    float* P       = ws + 16777216;            // 8 * 4096 floats
    float* stats   = P + 8 * 4096;             // 256 floats
    float* out     = (float*)d_out;

    k_setup   <<<16,   256, 0, stream>>>(C_re, C_im, logA, Aim, logdt, P, stats);
    k_states  <<<8192, 256, 0, stream>>>(x, P, states);
    k_carries <<<256,  256, 0, stream>>>(states, P, carries);
    k_scanout <<<2048, 256, 0, stream>>>(x, P, carries, yconv);
    k_pointwise<<<1024,256, 0, stream>>>(yconv, x, W, D, zbuf);
    k_stats   <<<1024, 256, 0, stream>>>(zbuf, stats);
    k_final   <<<8192, 256, 0, stream>>>(zbuf, x, stats, gamma, beta, out);
}

// Round 4
// 342.806 us; speedup vs baseline: 2.2029x; 1.1528x over previous
//
#include <hip/hip_runtime.h>
#include <math.h>

#define HCH   128
#define NMODE 32
#define BB    8
#define LLEN  8192
#define LC    256
#define CCH   (LLEN / LC)      // 32 chunks per row
#define ROWS  (BB * HCH)       // 1024

// complex state update: S = w*S + xv   (Si uses old Sr)
#define UPD(xv) { float _t = fmaf(-wi, Si, (xv)); float _sr = fmaf(wr, Sr, _t); \
                  Si = fmaf(wi, Sr, wr * Si); Sr = _sr; }

// VALU-pipe cross-lane add (DPP): quad swap pairs / quad swap halves / half-row mirror
#define DPP_ADD(v, ctrl) { int _t = __builtin_amdgcn_update_dpp(0, __float_as_int(v), \
                             (ctrl), 0xF, 0xF, true); (v) += __int_as_float(_t); }

// ---------------- K1: per-(h,n) parameters + zero BN stats ----------------
__global__ void k_setup(const float* __restrict__ C_re, const float* __restrict__ C_im,
                        const float* __restrict__ logA, const float* __restrict__ Aim,
                        const float* __restrict__ logdt,
                        float* __restrict__ P, float* __restrict__ stats) {
    int i = blockIdx.x * 256 + threadIdx.x;
    if (blockIdx.x == 0 && threadIdx.x < 2 * HCH) stats[threadIdx.x] = 0.f;
    if (i >= HCH * NMODE) return;
    int h = i / NMODE;
    float ar = expf(logA[i]);
    float ai = Aim[i];
    float dt = expf(logdt[h]);
    float dre = -ar * dt, dim = ai * dt;
    float er = expf(dre);
    float wr = er * cosf(dim), wi = er * sinf(dim);
    float eL = expf(dre * (float)LC);
    float wLr = eL * cosf(dim * (float)LC), wLi = eL * sinf(dim * (float)LC);
    // K = (w-1)/A, A = -ar + i*ai  ->  (w-1)*conj(A)/|A|^2
    float den  = ar * ar + ai * ai;
    float numr = -(wr - 1.f) * ar + wi * ai;
    float numi = -wi * ar - (wr - 1.f) * ai;
    float Kr = numr / den, Ki = numi / den;
    float c0r = C_re[i],             c0i = C_im[i];
    float c1r = C_re[HCH*NMODE + i], c1i = C_im[HCH*NMODE + i];
    P[0*4096 + i] = wr;   P[1*4096 + i] = wi;
    P[2*4096 + i] = wLr;  P[3*4096 + i] = wLi;
    P[4*4096 + i] = 2.f * (c0r * Kr - c0i * Ki);   // G0 (2x folded)
    P[5*4096 + i] = 2.f * (c0r * Ki + c0i * Kr);
    P[6*4096 + i] = 2.f * (c1r * Kr - c1i * Ki);   // G1
    P[7*4096 + i] = 2.f * (c1r * Ki + c1i * Kr);
}

// ---------------- K2a: per-chunk local states (both directions) ----------------
// wave = (row, chunk); lane = d*32 + n. causal scans ascending, anti descending.
__global__ __launch_bounds__(256) void k_states(const float* __restrict__ x,
                                                const float* __restrict__ P,
                                                float* __restrict__ states) {
    int wid  = (blockIdx.x << 2) + (threadIdx.x >> 6);
    int lane = threadIdx.x & 63;
    int c = wid & (CCH - 1);
    int row = wid >> 5;               // CCH = 32
    int h = row & (HCH - 1);
    int d = lane >> 5, n = lane & 31;
    int pi = h * NMODE + n;
    float wr = P[pi], wi = P[4096 + pi];
    const float* xr = x + (size_t)row * LLEN + c * LC;
    float Sr = 0.f, Si = 0.f;
    for (int j4 = 0; j4 < LC; j4 += 4) {
        int off = d ? (LC - 4 - j4) : j4;
        float4 v = *(const float4*)(xr + off);
        float a0 = d ? v.w : v.x;
        float a1 = d ? v.z : v.y;
        float a2 = d ? v.y : v.z;
        float a3 = d ? v.x : v.w;
        UPD(a0); UPD(a1); UPD(a2); UPD(a3);
    }
    size_t sidx = ((((size_t)row * 2 + d) * NMODE + n) * CCH + c) * 2;
    states[sidx] = Sr; states[sidx + 1] = Si;
}

// ---------------- K2b: carry propagation across chunks ----------------
// thread = (row, d, n); sequential over C=32 chunks.
// Output layout: carries[((row*2+d)*CCH + c)*64 + 2n {,+1}]  (modes contiguous per chunk)
__global__ void k_carries(const float* __restrict__ states, const float* __restrict__ P,
                          float* __restrict__ carries) {
    int i = blockIdx.x * 256 + threadIdx.x;   // over ROWS*2*NMODE = 65536
    int n = i & 31; int d = (i >> 5) & 1; int row = i >> 6;
    int h = row & (HCH - 1);
    int pi = h * NMODE + n;
    float wLr = P[2*4096 + pi], wLi = P[3*4096 + pi];
    const float* S = states + (size_t)i * CCH * 2;
    float* Ca = carries + ((size_t)row * 2 + d) * CCH * 64 + 2 * n;
    float cr = 0.f, ci = 0.f;
    if (d == 0) {
        for (int c = 0; c < CCH; c++) {        // carry[c] = state entering chunk c
            Ca[(size_t)c * 64] = cr; Ca[(size_t)c * 64 + 1] = ci;
            float nr = fmaf(wLr, cr, -wLi * ci) + S[2*c];
            float ni = fmaf(wLi, cr,  wLr * ci) + S[2*c + 1];
            cr = nr; ci = ni;
        }
    } else {
        for (int c = CCH - 1; c >= 0; c--) {   // carryU[c] = T at end (local t=255) of chunk c
            Ca[(size_t)c * 64] = cr; Ca[(size_t)c * 64 + 1] = ci;
            float nr = fmaf(wLr, cr, -wLi * ci) + S[2*c];
            float ni = fmaf(wLi, cr,  wLr * ci) + S[2*c + 1];
            cr = nr; ci = ni;
        }
    }
}

// ---------------- K2c: carry-initialized in-chunk scan -> y_conv ----------------
// block = (row, half): 4 waves cover 16 chunks x 2 dirs.
// lane group g = lane>>3 (8 lanes, 4 modes each): d = g&1, chunk = wslot*4 + (g>>1).
// Unified emit: v = e*x[t] + Re(sum H*S_pre); then S = w*S + x[t]; t += stp.
//   causal: H = G*w, e = sum Re(G)  (emit-after-update folded into coefficients)
//   anti:   H = G,   e = 0          (emit-before-update, consumes x[t] at emit t)
// Reduction over the 8-lane group runs entirely on the VALU via DPP; the two
// directions of one chunk accumulate into ONE LDS row via plain RMW — safe:
// same wave, program-ordered DS ops, addresses t vs 255-t never equal.
__global__ __launch_bounds__(256, 8) void k_scanout(const float* __restrict__ x,
                                                    const float* __restrict__ P,
                                                    const float* __restrict__ carries,
                                                    float* __restrict__ yconv) {
    __shared__ float ylds[16 * 257];           // [c_local][t], +1 pad
    int tid   = threadIdx.x;
    int wslot = tid >> 6;
    int lane  = tid & 63;
    int g  = lane >> 3;
    int lp = lane & 7;
    int row  = blockIdx.x >> 1;
    int half = blockIdx.x & 1;
    int h = row & (HCH - 1);
    int d = g & 1;
    int c_local = (wslot << 2) + (g >> 1);     // 0..15
    int c = (half << 4) + c_local;             // 0..31
    int n0 = lp << 2;
    int pi = h * NMODE + n0;

    float4 w_r = *(const float4*)&P[pi];
    float4 w_i = *(const float4*)&P[4096 + pi];
    float4 g_r = *(const float4*)&P[(4 + 2*d) * 4096 + pi];
    float4 g_i = *(const float4*)&P[(5 + 2*d) * 4096 + pi];
    float wr[4] = {w_r.x, w_r.y, w_r.z, w_r.w};
    float wi[4] = {w_i.x, w_i.y, w_i.z, w_i.w};
    float gr[4] = {g_r.x, g_r.y, g_r.z, g_r.w};
    float gi[4] = {g_i.x, g_i.y, g_i.z, g_i.w};
    float Hr[4], Hi[4], e;
    if (d == 0) {
        #pragma unroll
        for (int k = 0; k < 4; k++) {
            Hr[k] = gr[k] * wr[k] - gi[k] * wi[k];
            Hi[k] = gr[k] * wi[k] + gi[k] * wr[k];
        }
        e = gr[0] + gr[1] + gr[2] + gr[3];
    } else {
        #pragma unroll
        for (int k = 0; k < 4; k++) { Hr[k] = gr[k]; Hi[k] = gi[k]; }
        e = 0.f;
    }

    size_t cb = (((size_t)row * 2 + d) * CCH + c) * 64 + (n0 << 1);
    float4 ca  = *(const float4*)&carries[cb];
    float4 cbv = *(const float4*)&carries[cb + 4];
    float Sr[4] = {ca.x, ca.z, cbv.x, cbv.z};
    float Si[4] = {ca.y, ca.w, cbv.y, cbv.w};

    for (int i = tid; i < 16 * 257; i += 256) ylds[i] = 0.f;
    __syncthreads();

    const float* xr = x + (size_t)row * LLEN + ((size_t)c << 8);
    int stp = 1 - 2 * d;
    int t = d ? 255 : 0;
    int ybase = c_local * 257;

    for (int j = 0; j < 256; j += 4) {
        int xoff = d ? (252 - j) : j;
        float4 xv4 = *(const float4*)(xr + xoff);
        float xs0 = d ? xv4.w : xv4.x;
        float xs1 = d ? xv4.z : xv4.y;
        float xs2 = d ? xv4.y : xv4.z;
        float xs3 = d ? xv4.x : xv4.w;
        float xs[4] = {xs0, xs1, xs2, xs3};
        #pragma unroll
        for (int q = 0; q < 4; q++) {
            float xv = xs[q];
            float v = e * xv;
            #pragma unroll
            for (int k = 0; k < 4; k++)
                v = fmaf(Hr[k], Sr[k], fmaf(-Hi[k], Si[k], v));
            DPP_ADD(v, 0xB1);    // quad_perm [1,0,3,2]  (xor 1)
            DPP_ADD(v, 0x4E);    // quad_perm [2,3,0,1]  (xor 2)
            DPP_ADD(v, 0x141);   // row_half_mirror      (other quad)
            if (lp == 0) ylds[ybase + t] += v;
            #pragma unroll
            for (int k = 0; k < 4; k++) {
                float t0  = fmaf(-wi[k], Si[k], xv);
                float nsr = fmaf(wr[k], Sr[k], t0);
                Si[k] = fmaf(wi[k], Sr[k], wr[k] * Si[k]);
                Sr[k] = nsr;
            }
            t += stp;
        }
    }
    __syncthreads();
    // copy out: 16 chunks x 256 = 4096 floats; 256 threads x 4 floats x 4 passes
    float* yo = yconv + (size_t)row * LLEN + ((size_t)half << 12);
    #pragma unroll
    for (int base = 0; base < 4096; base += 1024) {
        int idx = base + (tid << 2);
        int cl  = idx >> 8;
        int tl0 = idx & 255;
        float4 o4;
        o4.x = ylds[cl * 257 + tl0];
        o4.y = ylds[cl * 257 + tl0 + 1];
        o4.z = ylds[cl * 257 + tl0 + 2];
        o4.w = ylds[cl * 257 + tl0 + 3];
        *(float4*)(yo + idx) = o4;
    }
}

// ---------------- K3: fused skip+GELU + 128x128 pointwise conv + BN stats ----------------
__global__ __launch_bounds__(256) void k_pointwise(const float* __restrict__ yconv,
                                                   const float* __restrict__ x,
                                                   const float* __restrict__ W,
                                                   const float* __restrict__ D,
                                                   float* __restrict__ z,
                                                   float* __restrict__ stats) {
    __shared__ float Wt[32][132];   // [h][o], padded (reused as stats scratch)
    __shared__ float Yt[32][68];    // [h][l], padded (16B-aligned rows)
    int b  = blockIdx.x >> 7;
    int l0 = (blockIdx.x & 127) << 6;
    int tid = threadIdx.x;
    int to4 = (tid & 31) << 2;      // owns o = to4..to4+3
    int tl  = tid >> 5;             // owns l = tl*8..tl*8+7
    float acc[4][8];
    #pragma unroll
    for (int a = 0; a < 4; a++)
        #pragma unroll
        for (int j = 0; j < 8; j++) acc[a][j] = 0.f;

    for (int ht = 0; ht < 4; ht++) {
        int hbase = ht * 32;
        __syncthreads();
        for (int i = tid; i < 4096; i += 256) {          // stage W tile
            int o = i >> 5, hh = i & 31;
            Wt[hh][o] = W[o * HCH + hbase + hh];
        }
        for (int i = tid; i < 2048; i += 256) {          // stage activated y tile
            int hh = i >> 6, l = i & 63;
            int hcur = hbase + hh;
            size_t gi = (size_t)(b * HCH + hcur) * LLEN + l0 + l;
            float yv = yconv[gi] + D[hcur] * x[gi];
            Yt[hh][l] = 0.5f * yv * (1.f + erff(yv * 0.70710678118654752f));
        }
        __syncthreads();
        #pragma unroll 8
        for (int hh = 0; hh < 32; hh++) {
            float4 wv = *(const float4*)&Wt[hh][to4];
            float4 ya = *(const float4*)&Yt[hh][tl * 8];
            float4 yb = *(const float4*)&Yt[hh][tl * 8 + 4];
            float wv4[4] = {wv.x, wv.y, wv.z, wv.w};
            float yv8[8] = {ya.x, ya.y, ya.z, ya.w, yb.x, yb.y, yb.z, yb.w};
            #pragma unroll
            for (int a = 0; a < 4; a++)
                #pragma unroll
                for (int j = 0; j < 8; j++)
                    acc[a][j] = fmaf(wv4[a], yv8[j], acc[a][j]);
        }
    }
    #pragma unroll
    for (int a = 0; a < 4; a++) {
        int o = to4 + a;
        size_t go = (size_t)(b * HCH + o) * LLEN + l0 + tl * 8;
        float4 s0 = {acc[a][0], acc[a][1], acc[a][2], acc[a][3]};
        float4 s1 = {acc[a][4], acc[a][5], acc[a][6], acc[a][7]};
        *(float4*)(z + go)     = s0;
        *(float4*)(z + go + 4) = s1;
    }
    // ---- fused BN stats: per-thread partials -> LDS (reuse Wt) -> global atomics ----
    __syncthreads();
    float* Ls = &Wt[0][0];          // need 2*8*132 = 2112 floats (have 4224)
    #pragma unroll
    for (int a = 0; a < 4; a++) {
        float s = 0.f, qq = 0.f;
        #pragma unroll
        for (int j = 0; j < 8; j++) { s += acc[a][j]; qq = fmaf(acc[a][j], acc[a][j], qq); }
        Ls[tl * 132 + to4 + a]        = s;
        Ls[1056 + tl * 132 + to4 + a] = qq;
    }
    __syncthreads();
    if (tid < HCH) {
        float s = 0.f, qq = 0.f;
        #pragma unroll
        for (int t = 0; t < 8; t++) { s += Ls[t * 132 + tid]; qq += Ls[1056 + t * 132 + tid]; }
        atomicAdd(&stats[tid], s);
        atomicAdd(&stats[HCH + tid], qq);
    }
}

// ---------------- K4: BN normalize + ELU + residual ----------------
__global__ __launch_bounds__(256) void k_final(const float* __restrict__ z,
                                               const float* __restrict__ x,
                                               const float* __restrict__ stats,
                                               const float* __restrict__ gamma,
                                               const float* __restrict__ beta,
                                               float* __restrict__ out) {
    size_t i4 = (size_t)blockIdx.x * 256 + threadIdx.x;
    if (i4 >= (size_t)BB * HCH * LLEN / 4) return;
    size_t flat = i4 * 4;
    int o = (int)((flat / LLEN) & (HCH - 1));
    const float inv_cnt = 1.f / (float)(BB * LLEN);
    float m   = stats[o] * inv_cnt;
    float var = stats[HCH + o] * inv_cnt - m * m;
    float rs  = rsqrtf(var + 1e-5f);
    float ga  = gamma[o] * rs;
    float bt  = beta[o] - m * ga;
    float4 zv = ((const float4*)z)[i4];
    float4 xv = ((const float4*)x)[i4];
    float4 r;
    { float t = fmaf(zv.x, ga, bt); float e = t > 0.f ? t : expm1f(t); r.x = e + xv.x; }
    { float t = fmaf(zv.y, ga, bt); float e = t > 0.f ? t : expm1f(t); r.y = e + xv.y; }
    { float t = fmaf(zv.z, ga, bt); float e = t > 0.f ? t : expm1f(t); r.z = e + xv.z; }
    { float t = fmaf(zv.w, ga, bt); float e = t > 0.f ? t : expm1f(t); r.w = e + xv.w; }
    ((float4*)out)[i4] = r;
}

extern "C" void kernel_launch(void* const* d_in, const int* in_sizes, int n_in,
                              void* d_out, int out_size, void* d_ws, size_t ws_size,
                              hipStream_t stream) {
    const float* x     = (const float*)d_in[0];
    const float* C_re  = (const float*)d_in[1];
    const float* C_im  = (const float*)d_in[2];
    const float* logA  = (const float*)d_in[3];
    const float* Aim   = (const float*)d_in[4];
    const float* logdt = (const float*)d_in[5];
    const float* D     = (const float*)d_in[6];
    const float* W     = (const float*)d_in[7];
    const float* gamma = (const float*)d_in[8];
    const float* beta  = (const float*)d_in[9];

    float* ws      = (float*)d_ws;
    float* yconv   = ws;                       // 8388608 floats (32 MB)
    float* zbuf    = ws + 8388608;             // 8388608 floats (32 MB)
    float* states  = zbuf;                     // aliased: dead before z written
    float* carries = zbuf + 4194304;           // aliased: dead before z written
    float* P       = ws + 16777216;            // 8 * 4096 floats
    float* stats   = P + 8 * 4096;             // 256 floats
    float* out     = (float*)d_out;

    k_setup   <<<16,   256, 0, stream>>>(C_re, C_im, logA, Aim, logdt, P, stats);
    k_states  <<<8192, 256, 0, stream>>>(x, P, states);
    k_carries <<<256,  256, 0, stream>>>(states, P, carries);
    k_scanout <<<2048, 256, 0, stream>>>(x, P, carries, yconv);
    k_pointwise<<<1024,256, 0, stream>>>(yconv, x, W, D, zbuf, stats);
    k_final   <<<8192, 256, 0, stream>>>(zbuf, x, stats, gamma, beta, out);
}

// Round 5
// 310.157 us; speedup vs baseline: 2.4348x; 1.1053x over previous
//
#include <hip/hip_runtime.h>
#include <math.h>

#define HCH   128
#define NMODE 32
#define BB    8
#define LLEN  8192
#define LC    256
#define CCH   (LLEN / LC)      // 32 chunks per row
#define ROWS  (BB * HCH)       // 1024
#define YPITCH 260             // LDS row pitch (16B-aligned, non-pow2 for banks)

typedef float v2f __attribute__((ext_vector_type(2)));

// packed complex state update for a mode-pair: S = w*S + x   (Si uses old Sr)
#define UPD2(S_r, S_i, W_r, W_i, XV2) { \
    v2f _t0 = (XV2) - (W_i) * (S_i); \
    v2f _nr = (W_r) * (S_r) + _t0; \
    (S_i) = (W_r) * (S_i) + (W_i) * (S_r); \
    (S_r) = _nr; }

// VALU-pipe cross-lane add (DPP): xor1 / xor2 / half-row mirror => 8-lane total in all lanes
#define DPP_ADD(v, ctrl) { int _t = __builtin_amdgcn_update_dpp(0, __float_as_int(v), \
                             (ctrl), 0xF, 0xF, true); (v) += __int_as_float(_t); }

// branch-free GELU, exact-erf flavor via A&S 7.1.25 (|erf err| <= 5e-4)
__device__ __forceinline__ float gelu_f(float y) {
    float z = fabsf(y) * 0.7071067811865476f;
    float p = fmaf(z, 0.078108f, 0.000972f);
    p = fmaf(z, p, 0.230389f);
    p = fmaf(z, p, 0.278393f);
    p = fmaf(z, p, 1.0f);
    float p2 = p * p;
    float p4 = p2 * p2;
    float er = 1.f - __builtin_amdgcn_rcpf(p4);
    float s  = copysignf(er, y);
    return 0.5f * y * (1.f + s);
}

// ---------------- K1: per-(h,n) parameters + zero BN stats ----------------
__global__ void k_setup(const float* __restrict__ C_re, const float* __restrict__ C_im,
                        const float* __restrict__ logA, const float* __restrict__ Aim,
                        const float* __restrict__ logdt,
                        float* __restrict__ P, float* __restrict__ stats) {
    int i = blockIdx.x * 256 + threadIdx.x;
    if (blockIdx.x == 0 && threadIdx.x < 2 * HCH) stats[threadIdx.x] = 0.f;
    if (i >= HCH * NMODE) return;
    int h = i / NMODE;
    float ar = expf(logA[i]);
    float ai = Aim[i];
    float dt = expf(logdt[h]);
    float dre = -ar * dt, dim = ai * dt;
    float er = expf(dre);
    float wr = er * cosf(dim), wi = er * sinf(dim);
    float eL = expf(dre * (float)LC);
    float wLr = eL * cosf(dim * (float)LC), wLi = eL * sinf(dim * (float)LC);
    float den  = ar * ar + ai * ai;
    float numr = -(wr - 1.f) * ar + wi * ai;
    float numi = -wi * ar - (wr - 1.f) * ai;
    float Kr = numr / den, Ki = numi / den;
    float c0r = C_re[i],             c0i = C_im[i];
    float c1r = C_re[HCH*NMODE + i], c1i = C_im[HCH*NMODE + i];
    P[0*4096 + i] = wr;   P[1*4096 + i] = wi;
    P[2*4096 + i] = wLr;  P[3*4096 + i] = wLi;
    P[4*4096 + i] = 2.f * (c0r * Kr - c0i * Ki);   // G0 (2x folded)
    P[5*4096 + i] = 2.f * (c0r * Ki + c0i * Kr);
    P[6*4096 + i] = 2.f * (c1r * Kr - c1i * Ki);   // G1
    P[7*4096 + i] = 2.f * (c1r * Ki + c1i * Kr);
}

// ---------------- K2a: per-chunk local states (both directions), packed ----------------
// wave = (row, chunk-pair). lane: cs = lane>>5 (chunk of pair), d = (lane>>4)&1,
// m = lane&15 -> mode pair (2m, 2m+1). causal ascending, anti descending.
__global__ __launch_bounds__(256) void k_states(const float* __restrict__ x,
                                                const float* __restrict__ P,
                                                float* __restrict__ states) {
    int wid  = (blockIdx.x << 2) + (threadIdx.x >> 6);
    int lane = threadIdx.x & 63;
    int cpair = wid & 15;
    int row   = wid >> 4;
    int h  = row & (HCH - 1);
    int cs = lane >> 5;
    int d  = (lane >> 4) & 1;
    int m  = lane & 15;
    int n0 = m << 1;
    int c  = (cpair << 1) + cs;
    int pi = h * NMODE + n0;
    v2f wr2 = *(const v2f*)&P[pi];
    v2f wi2 = *(const v2f*)&P[4096 + pi];
    const float* xr = x + (size_t)row * LLEN + c * LC;
    v2f Sr2 = {0.f, 0.f}, Si2 = {0.f, 0.f};
    for (int j4 = 0; j4 < LC; j4 += 4) {
        int off = d ? (252 - j4) : j4;
        float4 v = *(const float4*)(xr + off);
        float a0 = d ? v.w : v.x;
        float a1 = d ? v.z : v.y;
        float a2 = d ? v.y : v.z;
        float a3 = d ? v.x : v.w;
        v2f x0 = {a0, a0}; UPD2(Sr2, Si2, wr2, wi2, x0);
        v2f x1 = {a1, a1}; UPD2(Sr2, Si2, wr2, wi2, x1);
        v2f x2 = {a2, a2}; UPD2(Sr2, Si2, wr2, wi2, x2);
        v2f x3 = {a3, a3}; UPD2(Sr2, Si2, wr2, wi2, x3);
    }
    size_t b0 = ((((size_t)row * 2 + d) * NMODE + n0) * CCH + c) * 2;
    *(float2*)&states[b0]                = make_float2(Sr2.x, Si2.x);
    *(float2*)&states[b0 + 2 * CCH]      = make_float2(Sr2.y, Si2.y);
}

// ---------------- K2b: carry propagation across chunks ----------------
// thread = (row, d, n); sequential over C=32 chunks.
// Output layout: carries[((row*2+d)*CCH + c)*64 + 2n {,+1}]
__global__ void k_carries(const float* __restrict__ states, const float* __restrict__ P,
                          float* __restrict__ carries) {
    int i = blockIdx.x * 256 + threadIdx.x;   // over ROWS*2*NMODE = 65536
    int n = i & 31; int d = (i >> 5) & 1; int row = i >> 6;
    int h = row & (HCH - 1);
    int pi = h * NMODE + n;
    float wLr = P[2*4096 + pi], wLi = P[3*4096 + pi];
    const float* S = states + (size_t)i * CCH * 2;
    float* Ca = carries + ((size_t)row * 2 + d) * CCH * 64 + 2 * n;
    float cr = 0.f, ci = 0.f;
    if (d == 0) {
        for (int c = 0; c < CCH; c++) {        // carry[c] = state entering chunk c
            Ca[(size_t)c * 64] = cr; Ca[(size_t)c * 64 + 1] = ci;
            float nr = fmaf(wLr, cr, -wLi * ci) + S[2*c];
            float ni = fmaf(wLi, cr,  wLr * ci) + S[2*c + 1];
            cr = nr; ci = ni;
        }
    } else {
        for (int c = CCH - 1; c >= 0; c--) {   // carryU[c] = T at local t=255 of chunk c
            Ca[(size_t)c * 64] = cr; Ca[(size_t)c * 64 + 1] = ci;
            float nr = fmaf(wLr, cr, -wLi * ci) + S[2*c];
            float ni = fmaf(wLi, cr,  wLr * ci) + S[2*c + 1];
            cr = nr; ci = ni;
        }
    }
}

// ---------------- K2c: carry-initialized in-chunk scan -> y_conv ----------------
// block = (row, half): 4 waves x 8 groups of 8 lanes; group: d = g&1, chunk = wslot*4+(g>>1);
// lane-in-group lp holds mode-pairs (4lp..4lp+3) as two packed pairs.
// Unified emit: v = e*x[t] + Re(sum H*S_pre); then S = w*S + x[t].
//   causal: H = G*w, e = sum Re(G); anti: H = G, e = 0.
// 8-lane DPP reduction leaves the sum in ALL lanes; 4 outputs buffered in regs and
// committed as one float4 LDS RMW per 4 steps (causal/anti blocks never overlap).
__global__ __launch_bounds__(256, 8) void k_scanout(const float* __restrict__ x,
                                                    const float* __restrict__ P,
                                                    const float* __restrict__ carries,
                                                    float* __restrict__ yconv) {
    __shared__ float ylds[16 * YPITCH];
    int tid   = threadIdx.x;
    int wslot = tid >> 6;
    int lane  = tid & 63;
    int g  = lane >> 3;
    int lp = lane & 7;
    int row  = blockIdx.x >> 1;
    int half = blockIdx.x & 1;
    int h = row & (HCH - 1);
    int d = g & 1;
    int c_local = (wslot << 2) + (g >> 1);     // 0..15
    int c = (half << 4) + c_local;             // 0..31
    int n0 = lp << 2;
    int pi = h * NMODE + n0;

    float4 w_r = *(const float4*)&P[pi];
    float4 w_i = *(const float4*)&P[4096 + pi];
    float4 g_r = *(const float4*)&P[(4 + 2*d) * 4096 + pi];
    float4 g_i = *(const float4*)&P[(5 + 2*d) * 4096 + pi];
    v2f wr2[2] = {{w_r.x, w_r.y}, {w_r.z, w_r.w}};
    v2f wi2[2] = {{w_i.x, w_i.y}, {w_i.z, w_i.w}};
    v2f Hr2[2], Hi2[2];
    float e;
    if (d == 0) {   // H = G*w, e = sum Re(G)
        Hr2[0] = (v2f){g_r.x * w_r.x - g_i.x * w_i.x, g_r.y * w_r.y - g_i.y * w_i.y};
        Hr2[1] = (v2f){g_r.z * w_r.z - g_i.z * w_i.z, g_r.w * w_r.w - g_i.w * w_i.w};
        Hi2[0] = (v2f){g_r.x * w_i.x + g_i.x * w_r.x, g_r.y * w_i.y + g_i.y * w_r.y};
        Hi2[1] = (v2f){g_r.z * w_i.z + g_i.z * w_r.z, g_r.w * w_i.w + g_i.w * w_r.w};
        e = g_r.x + g_r.y + g_r.z + g_r.w;
    } else {
        Hr2[0] = (v2f){g_r.x, g_r.y}; Hr2[1] = (v2f){g_r.z, g_r.w};
        Hi2[0] = (v2f){g_i.x, g_i.y}; Hi2[1] = (v2f){g_i.z, g_i.w};
        e = 0.f;
    }

    size_t cb = (((size_t)row * 2 + d) * CCH + c) * 64 + (n0 << 1);
    float4 ca  = *(const float4*)&carries[cb];
    float4 cbv = *(const float4*)&carries[cb + 4];
    v2f Sr2[2] = {{ca.x, ca.z}, {cbv.x, cbv.z}};
    v2f Si2[2] = {{ca.y, ca.w}, {cbv.y, cbv.w}};

    for (int i = tid; i < 16 * YPITCH; i += 256) ylds[i] = 0.f;
    __syncthreads();

    const float* xr = x + (size_t)row * LLEN + ((size_t)c << 8);
    int ybase = c_local * YPITCH;

    for (int j = 0; j < 256; j += 4) {
        int xoff = d ? (252 - j) : j;
        float4 xv4 = *(const float4*)(xr + xoff);
        float xs0 = d ? xv4.w : xv4.x;
        float xs1 = d ? xv4.z : xv4.y;
        float xs2 = d ? xv4.y : xv4.z;
        float xs3 = d ? xv4.x : xv4.w;
        float v0, v1, v2, v3;
#define EMIT_UPD(XV, VOUT) { \
        v2f acc = Hr2[0] * Sr2[0]; \
        acc = acc - Hi2[0] * Si2[0]; \
        acc = Hr2[1] * Sr2[1] + acc; \
        acc = acc - Hi2[1] * Si2[1]; \
        float vv = fmaf(e, (XV), acc.x + acc.y); \
        DPP_ADD(vv, 0xB1); DPP_ADD(vv, 0x4E); DPP_ADD(vv, 0x141); \
        VOUT = vv; \
        v2f xv2 = {(XV), (XV)}; \
        UPD2(Sr2[0], Si2[0], wr2[0], wi2[0], xv2); \
        UPD2(Sr2[1], Si2[1], wr2[1], wi2[1], xv2); }
        EMIT_UPD(xs0, v0); EMIT_UPD(xs1, v1); EMIT_UPD(xs2, v2); EMIT_UPD(xs3, v3);
#undef EMIT_UPD
        float a0 = d ? v3 : v0;
        float a1 = d ? v2 : v1;
        float a2 = d ? v1 : v2;
        float a3 = d ? v0 : v3;
        if (lp == 0) {
            float4* yp = (float4*)&ylds[ybase + xoff];
            float4 cur = *yp;
            cur.x += a0; cur.y += a1; cur.z += a2; cur.w += a3;
            *yp = cur;
        }
    }
    __syncthreads();
    // copy out: 16 chunks x 256 = 4096 floats; 256 threads x 4 floats x 4 passes
    float* yo = yconv + (size_t)row * LLEN + ((size_t)half << 12);
    #pragma unroll
    for (int base = 0; base < 4096; base += 1024) {
        int idx = base + (tid << 2);
        int cl  = idx >> 8;
        int tl0 = idx & 255;
        float4 o4;
        o4.x = ylds[cl * YPITCH + tl0];
        o4.y = ylds[cl * YPITCH + tl0 + 1];
        o4.z = ylds[cl * YPITCH + tl0 + 2];
        o4.w = ylds[cl * YPITCH + tl0 + 3];
        *(float4*)(yo + idx) = o4;
    }
}

// ---------------- K3: fused skip+GELU + 128x128 pointwise conv + BN stats ----------------
__global__ __launch_bounds__(256) void k_pointwise(const float* __restrict__ yconv,
                                                   const float* __restrict__ x,
                                                   const float* __restrict__ W,
                                                   const float* __restrict__ D,
                                                   float* __restrict__ z,
                                                   float* __restrict__ stats) {
    __shared__ float Wt[32][132];   // [h][o], padded (reused as stats scratch)
    __shared__ float Yt[32][68];    // [h][l], padded
    int b  = blockIdx.x >> 7;
    int l0 = (blockIdx.x & 127) << 6;
    int tid = threadIdx.x;
    int to4 = (tid & 31) << 2;      // owns o = to4..to4+3
    int tl  = tid >> 5;             // owns l = tl*8..tl*8+7
    float acc[4][8];
    #pragma unroll
    for (int a = 0; a < 4; a++)
        #pragma unroll
        for (int j = 0; j < 8; j++) acc[a][j] = 0.f;

    for (int ht = 0; ht < 4; ht++) {
        int hbase = ht * 32;
        __syncthreads();
        for (int i = tid; i < 4096; i += 256) {          // stage W tile
            int o = i >> 5, hh = i & 31;
            Wt[hh][o] = W[o * HCH + hbase + hh];
        }
        for (int i = tid; i < 2048; i += 256) {          // stage activated y tile
            int hh = i >> 6, l = i & 63;
            int hcur = hbase + hh;
            size_t gi = (size_t)(b * HCH + hcur) * LLEN + l0 + l;
            float yv = yconv[gi] + D[hcur] * x[gi];
            Yt[hh][l] = gelu_f(yv);
        }
        __syncthreads();
        #pragma unroll 8
        for (int hh = 0; hh < 32; hh++) {
            float4 wv = *(const float4*)&Wt[hh][to4];
            float4 ya = *(const float4*)&Yt[hh][tl * 8];
            float4 yb = *(const float4*)&Yt[hh][tl * 8 + 4];
            float wv4[4] = {wv.x, wv.y, wv.z, wv.w};
            float yv8[8] = {ya.x, ya.y, ya.z, ya.w, yb.x, yb.y, yb.z, yb.w};
            #pragma unroll
            for (int a = 0; a < 4; a++)
                #pragma unroll
                for (int j = 0; j < 8; j++)
                    acc[a][j] = fmaf(wv4[a], yv8[j], acc[a][j]);
        }
    }
    #pragma unroll
    for (int a = 0; a < 4; a++) {
        int o = to4 + a;
        size_t go = (size_t)(b * HCH + o) * LLEN + l0 + tl * 8;
        float4 s0 = {acc[a][0], acc[a][1], acc[a][2], acc[a][3]};
        float4 s1 = {acc[a][4], acc[a][5], acc[a][6], acc[a][7]};
        *(float4*)(z + go)     = s0;
        *(float4*)(z + go + 4) = s1;
    }
    // ---- fused BN stats: per-thread partials -> LDS (reuse Wt) -> global atomics ----
    __syncthreads();
    float* Ls = &Wt[0][0];          // need 2*8*132 = 2112 floats (have 4224)
    #pragma unroll
    for (int a = 0; a < 4; a++) {
        float s = 0.f, qq = 0.f;
        #pragma unroll
        for (int j = 0; j < 8; j++) { s += acc[a][j]; qq = fmaf(acc[a][j], acc[a][j], qq); }
        Ls[tl * 132 + to4 + a]        = s;
        Ls[1056 + tl * 132 + to4 + a] = qq;
    }
    __syncthreads();
    if (tid < HCH) {
        float s = 0.f, qq = 0.f;
        #pragma unroll
        for (int t = 0; t < 8; t++) { s += Ls[t * 132 + tid]; qq += Ls[1056 + t * 132 + tid]; }
        atomicAdd(&stats[tid], s);
        atomicAdd(&stats[HCH + tid], qq);
    }
}

// ---------------- K4: BN normalize + ELU + residual ----------------
__global__ __launch_bounds__(256) void k_final(const float* __restrict__ z,
                                               const float* __restrict__ x,
                                               const float* __restrict__ stats,
                                               const float* __restrict__ gamma,
                                               const float* __restrict__ beta,
                                               float* __restrict__ out) {
    size_t i4 = (size_t)blockIdx.x * 256 + threadIdx.x;
    if (i4 >= (size_t)BB * HCH * LLEN / 4) return;
    size_t flat = i4 * 4;
    int o = (int)((flat / LLEN) & (HCH - 1));
    const float inv_cnt = 1.f / (float)(BB * LLEN);
    float m   = stats[o] * inv_cnt;
    float var = stats[HCH + o] * inv_cnt - m * m;
    float rs  = rsqrtf(var + 1e-5f);
    float ga  = gamma[o] * rs;
    float bt  = beta[o] - m * ga;
    float4 zv = ((const float4*)z)[i4];
    float4 xv = ((const float4*)x)[i4];
    float4 r;
    { float t = fmaf(zv.x, ga, bt); float e = t > 0.f ? t : (__expf(t) - 1.f); r.x = e + xv.x; }
    { float t = fmaf(zv.y, ga, bt); float e = t > 0.f ? t : (__expf(t) - 1.f); r.y = e + xv.y; }
    { float t = fmaf(zv.z, ga, bt); float e = t > 0.f ? t : (__expf(t) - 1.f); r.z = e + xv.z; }
    { float t = fmaf(zv.w, ga, bt); float e = t > 0.f ? t : (__expf(t) - 1.f); r.w = e + xv.w; }
    ((float4*)out)[i4] = r;
}

extern "C" void kernel_launch(void* const* d_in, const int* in_sizes, int n_in,
                              void* d_out, int out_size, void* d_ws, size_t ws_size,
                              hipStream_t stream) {
    const float* x     = (const float*)d_in[0];
    const float* C_re  = (const float*)d_in[1];
    const float* C_im  = (const float*)d_in[2];
    const float* logA  = (const float*)d_in[3];
    const float* Aim   = (const float*)d_in[4];
    const float* logdt = (const float*)d_in[5];
    const float* D     = (const float*)d_in[6];
    const float* W     = (const float*)d_in[7];
    const float* gamma = (const float*)d_in[8];
    const float* beta  = (const float*)d_in[9];

    float* ws      = (float*)d_ws;
    float* yconv   = ws;                       // 8388608 floats (32 MB)
    float* zbuf    = ws + 8388608;             // 8388608 floats (32 MB)
    float* states  = zbuf;                     // aliased: dead before z written
    float* carries = zbuf + 4194304;           // aliased: dead before z written
    float* P       = ws + 16777216;            // 8 * 4096 floats
    float* stats   = P + 8 * 4096;             // 256 floats
    float* out     = (float*)d_out;

    k_setup   <<<16,   256, 0, stream>>>(C_re, C_im, logA, Aim, logdt, P, stats);
    k_states  <<<4096, 256, 0, stream>>>(x, P, states);
    k_carries <<<256,  256, 0, stream>>>(states, P, carries);
    k_scanout <<<2048, 256, 0, stream>>>(x, P, carries, yconv);
    k_pointwise<<<1024,256, 0, stream>>>(yconv, x, W, D, zbuf, stats);
    k_final   <<<8192, 256, 0, stream>>>(zbuf, x, stats, gamma, beta, out);
}

// Round 6
// 238.317 us; speedup vs baseline: 3.1687x; 1.3014x over previous
//
#include <hip/hip_runtime.h>
#include <math.h>

#define HCH   128
#define NMODE 32
#define BB    8
#define LLEN  8192
#define LC    256
#define CCH   (LLEN / LC)      // 32 chunks per row
#define ROWS  (BB * HCH)       // 1024

typedef unsigned int uint;
typedef _Float16 f16x8 __attribute__((ext_vector_type(8)));
typedef float    f32x4 __attribute__((ext_vector_type(4)));

static __device__ __forceinline__ uint pk2(float a, float b) {
    union { _Float16 h[2]; uint u; } v;
    v.h[0] = (_Float16)a; v.h[1] = (_Float16)b;
    return v.u;
}

// w^e by fixed 8-step binary exponentiation (e in [0,255])
static __device__ __forceinline__ void cpow8(float wr, float wi, int e, float& pr, float& pi) {
    pr = 1.f; pi = 0.f;
    float br = wr, bi = wi;
    #pragma unroll
    for (int k = 0; k < 8; k++) {
        if (e & (1 << k)) { float t = pr * br - pi * bi; pi = pr * bi + pi * br; pr = t; }
        float t2 = br * br - bi * bi; bi = 2.f * br * bi; br = t2;
    }
}

// ---------------- K1: per-(h,n) parameters + zero BN stats ----------------
__global__ void k_setup(const float* __restrict__ C_re, const float* __restrict__ C_im,
                        const float* __restrict__ logA, const float* __restrict__ Aim,
                        const float* __restrict__ logdt,
                        float* __restrict__ P, float* __restrict__ stats) {
    int i = blockIdx.x * 256 + threadIdx.x;
    if (blockIdx.x == 0 && threadIdx.x < 2 * HCH) stats[threadIdx.x] = 0.f;
    if (i >= HCH * NMODE) return;
    int h = i / NMODE;
    float ar = expf(logA[i]);
    float ai = Aim[i];
    float dt = expf(logdt[h]);
    float dre = -ar * dt, dim = ai * dt;
    float er = expf(dre);
    float wr = er * cosf(dim), wi = er * sinf(dim);
    float eL = expf(dre * (float)LC);
    float wLr = eL * cosf(dim * (float)LC), wLi = eL * sinf(dim * (float)LC);
    // K = (w-1)/A, A = -ar + i*ai  ->  (w-1)*conj(A)/|A|^2
    float den  = ar * ar + ai * ai;
    float numr = -(wr - 1.f) * ar + wi * ai;
    float numi = -wi * ar - (wr - 1.f) * ai;
    float Kr = numr / den, Ki = numi / den;
    float c0r = C_re[i],             c0i = C_im[i];
    float c1r = C_re[HCH*NMODE + i], c1i = C_im[HCH*NMODE + i];
    P[0*4096 + i] = wr;   P[1*4096 + i] = wi;
    P[2*4096 + i] = wLr;  P[3*4096 + i] = wLi;
    P[4*4096 + i] = 2.f * (c0r * Kr - c0i * Ki);   // G0 (2x folded)
    P[5*4096 + i] = 2.f * (c0r * Ki + c0i * Kr);
    P[6*4096 + i] = 2.f * (c1r * Kr - c1i * Ki);   // G1
    P[7*4096 + i] = 2.f * (c1r * Ki + c1i * Kr);
}

// ---------------- K2: build per-h GEMM operand matrices (f16) ----------------
// aT[(h*256 + t)*384 + k], t-major, k-contiguous:
//   k in [0,256):   M[t][s=k] = k0[t-s] if s<=t else k1[s-t-1]
//   k = 256+2n:     Re(H0_n w^t)     (coeff of Re(c0));  +1: -Im(H0_n w^t)   (coeff of Im(c0))
//   k = 320+2n:     Re(G1_n w^{255-t});                  +1: -Im(G1_n w^{255-t})
// eT[(h*128 + srow)*256 + s]:
//   srow=2n: Re(w^{255-s}); 2n+1: Im(w^{255-s}); 64+2n: Re(w^s); 64+2n+1: Im(w^s)
__global__ __launch_bounds__(256) void k_prep(const float* __restrict__ P,
                                              _Float16* __restrict__ aT,
                                              _Float16* __restrict__ eT) {
    __shared__ float wrL[32], wiL[32];
    __shared__ float G0r[32], G0i[32], G1r[32], G1i[32], H0r[32], H0i[32];
    __shared__ float k0L[256], k1L[256];
    int tid = threadIdx.x;
    int h = blockIdx.x;
    if (tid < 32) {
        int pi = h * 32 + tid;
        float wr = P[pi], wi = P[4096 + pi];
        float g0r = P[4*4096 + pi], g0i = P[5*4096 + pi];
        wrL[tid] = wr; wiL[tid] = wi;
        G0r[tid] = g0r; G0i[tid] = g0i;
        G1r[tid] = P[6*4096 + pi]; G1i[tid] = P[7*4096 + pi];
        H0r[tid] = g0r * wr - g0i * wi;
        H0i[tid] = g0r * wi + g0i * wr;
    }
    __syncthreads();
    // k0[tau] = Re(sum G0 w^tau); k1[tau] = Re(sum G1 w^tau)
    {
        int tau = tid;
        float s0 = 0.f, s1 = 0.f;
        for (int n = 0; n < 32; n++) {
            float pr, pi2; cpow8(wrL[n], wiL[n], tau, pr, pi2);
            s0 += G0r[n] * pr - G0i[n] * pi2;
            s1 += G1r[n] * pr - G1i[n] * pi2;
        }
        k0L[tau] = s0; k1L[tau] = s1;
    }
    __syncthreads();
    // Toeplitz part: 256 t x 256 s, write as uint (2 halves)
    for (int idx = tid; idx < 256 * 128; idx += 256) {
        int t  = idx >> 7;
        int sp = (idx & 127) << 1;
        float v0 = (sp     <= t) ? k0L[t - sp]     : k1L[sp - t - 1];
        float v1 = (sp + 1 <= t) ? k0L[t - sp - 1] : k1L[sp - t];
        *(uint*)&aT[((size_t)(h * 256 + t)) * 384 + sp] = pk2(v0, v1);
    }
    // carry-coefficient columns
    {
        int t = tid;
        size_t rb = ((size_t)(h * 256 + t)) * 384;
        for (int n = 0; n < 32; n++) {
            float wtr, wti, wur, wui;
            cpow8(wrL[n], wiL[n], t, wtr, wti);
            cpow8(wrL[n], wiL[n], 255 - t, wur, wui);
            float v0r = H0r[n] * wtr - H0i[n] * wti;
            float v0i = -(H0r[n] * wti + H0i[n] * wtr);
            float v1r = G1r[n] * wur - G1i[n] * wui;
            float v1i = -(G1r[n] * wui + G1i[n] * wur);
            *(uint*)&aT[rb + 256 + 2 * n] = pk2(v0r, v0i);
            *(uint*)&aT[rb + 320 + 2 * n] = pk2(v1r, v1i);
        }
    }
    // ET (state-gather Vandermonde)
    for (int idx = tid; idx < 32 * 256; idx += 256) {
        int n = idx >> 8, s = idx & 255;
        float ar, ai2, br, bi2;
        cpow8(wrL[n], wiL[n], 255 - s, ar, ai2);
        cpow8(wrL[n], wiL[n], s, br, bi2);
        size_t base = (size_t)h * 128 * 256;
        eT[base + (size_t)(2 * n) * 256 + s]      = (_Float16)ar;
        eT[base + (size_t)(2 * n + 1) * 256 + s]  = (_Float16)ai2;
        eT[base + (size_t)(64 + 2 * n) * 256 + s] = (_Float16)br;
        eT[base + (size_t)(65 + 2 * n) * 256 + s] = (_Float16)bi2;
    }
}

// ---------------- K3: chunk-end states via MFMA GEMM ----------------
// per block: h = bid>>1, mt = bid&1. C[m=bc(128 tile)][n=srow(128)] = X[bc][s] * ET[srow][s]
// S_end[(h*256 + bc)*128 + srow] (f32)
__global__ __launch_bounds__(256, 2) void k_states_g(const float* __restrict__ x,
                                                     const _Float16* __restrict__ eT,
                                                     float* __restrict__ S_end) {
    __shared__ _Float16 At[128 * 40];
    __shared__ _Float16 Bt[128 * 40];
    int tid = threadIdx.x;
    int bid = blockIdx.x;
    int h = bid >> 1, mt = bid & 1;
    int wave = tid >> 6, lane = tid & 63;
    int wm = wave >> 1, wn = wave & 1;
    int lrow = lane & 15, quad = lane >> 4;
    int koff = quad * 8;
    f32x4 acc[4][4];
    #pragma unroll
    for (int a = 0; a < 4; a++)
        #pragma unroll
        for (int b = 0; b < 4; b++) acc[a][b] = (f32x4){0.f, 0.f, 0.f, 0.f};

    for (int kk = 0; kk < 256; kk += 32) {
        __syncthreads();
        #pragma unroll
        for (int i = 0; i < 4; i++) {               // A: x rows (fp32 -> f16)
            int idx = tid + i * 256;
            int r = idx >> 3, seg = idx & 7;
            int bc = mt * 128 + r;
            const float* xp = x + (((size_t)((bc >> 5) * HCH + h)) << 13) + ((bc & 31) << 8) + kk + seg * 4;
            float4 v = *(const float4*)xp;
            uint2 o; o.x = pk2(v.x, v.y); o.y = pk2(v.z, v.w);
            *(uint2*)&At[r * 40 + seg * 4] = o;
        }
        #pragma unroll
        for (int i = 0; i < 2; i++) {               // B: eT rows (f16 direct)
            int idx = tid + i * 256;
            int r = idx >> 2, sg = idx & 3;
            uint4 v = *(const uint4*)(eT + ((size_t)(h * 128 + r)) * 256 + kk + sg * 8);
            *(uint4*)&Bt[r * 40 + sg * 8] = v;
        }
        __syncthreads();
        f16x8 a[4], b[4];
        #pragma unroll
        for (int f = 0; f < 4; f++) {
            a[f] = *(const f16x8*)&At[(wm * 64 + f * 16 + lrow) * 40 + koff];
            b[f] = *(const f16x8*)&Bt[(wn * 64 + f * 16 + lrow) * 40 + koff];
        }
        #pragma unroll
        for (int fi = 0; fi < 4; fi++)
            #pragma unroll
            for (int fj = 0; fj < 4; fj++)
                acc[fi][fj] = __builtin_amdgcn_mfma_f32_16x16x32_f16(a[fi], b[fj], acc[fi][fj], 0, 0, 0);
    }
    #pragma unroll
    for (int fi = 0; fi < 4; fi++) {
        #pragma unroll
        for (int fj = 0; fj < 4; fj++) {
            int srow = wn * 64 + fj * 16 + lrow;
            #pragma unroll
            for (int rg = 0; rg < 4; rg++) {
                int bc = mt * 128 + wm * 64 + fi * 16 + quad * 4 + rg;
                S_end[((size_t)(h * 256 + bc)) * 128 + srow] = acc[fi][fj][rg];
            }
        }
    }
}

// ---------------- K4: carry propagation (fp32) -> f16 carry columns ----------------
__global__ void k_carries(const float* __restrict__ S_end, const float* __restrict__ P,
                          _Float16* __restrict__ carr) {
    int i = blockIdx.x * 256 + threadIdx.x;   // over ROWS*2*NMODE = 65536
    int n = i & 31; int d = (i >> 5) & 1; int row = i >> 6;  // row = b*128 + h
    int h = row & (HCH - 1), b = row >> 7;
    int pi = h * NMODE + n;
    float wLr = P[2*4096 + pi], wLi = P[3*4096 + pi];
    int srow = d * 64 + 2 * n;
    float cr = 0.f, ci = 0.f;
    if (d == 0) {
        for (int c = 0; c < CCH; c++) {           // carry entering chunk c
            size_t base = ((size_t)(h * 256 + b * 32 + c)) * 128 + srow;
            carr[base] = (_Float16)cr; carr[base + 1] = (_Float16)ci;
            float sr = S_end[base], si = S_end[base + 1];
            float nr = fmaf(wLr, cr, -wLi * ci) + sr;
            float ni = fmaf(wLi, cr,  wLr * ci) + si;
            cr = nr; ci = ni;
        }
    } else {
        for (int c = CCH - 1; c >= 0; c--) {      // T at local t=255 of chunk c
            size_t base = ((size_t)(h * 256 + b * 32 + c)) * 128 + srow;
            carr[base] = (_Float16)cr; carr[base + 1] = (_Float16)ci;
            float sr = S_end[base], si = S_end[base + 1];
            float nr = fmaf(wLr, cr, -wLi * ci) + sr;
            float ni = fmaf(wLi, cr,  wLr * ci) + si;
            cr = nr; ci = ni;
        }
    }
}

// ---------------- K5: bidirectional conv via MFMA GEMM (K=384) ----------------
// block: h = bid>>2, mt = (bid>>1)&1, nt = bid&1.
// C[m=bc][n=t] = sum_k X'[bc][k] * aT[t][k];  X' cols: 0..255 from x (cvt), 256..383 from carr.
__global__ __launch_bounds__(256, 2) void k_conv_g(const float* __restrict__ x,
                                                   const _Float16* __restrict__ aT,
                                                   const _Float16* __restrict__ carr,
                                                   float* __restrict__ yconv) {
    __shared__ _Float16 At[128 * 40];
    __shared__ _Float16 Bt[128 * 40];
    int tid = threadIdx.x;
    int bid = blockIdx.x;
    int h = bid >> 2, mt = (bid >> 1) & 1, nt = bid & 1;
    int wave = tid >> 6, lane = tid & 63;
    int wm = wave >> 1, wn = wave & 1;
    int lrow = lane & 15, quad = lane >> 4;
    int koff = quad * 8;
    f32x4 acc[4][4];
    #pragma unroll
    for (int a = 0; a < 4; a++)
        #pragma unroll
        for (int b = 0; b < 4; b++) acc[a][b] = (f32x4){0.f, 0.f, 0.f, 0.f};

    for (int kk = 0; kk < 384; kk += 32) {
        __syncthreads();
        if (kk < 256) {
            #pragma unroll
            for (int i = 0; i < 4; i++) {           // A from x (fp32 -> f16)
                int idx = tid + i * 256;
                int r = idx >> 3, seg = idx & 7;
                int bc = mt * 128 + r;
                const float* xp = x + (((size_t)((bc >> 5) * HCH + h)) << 13) + ((bc & 31) << 8) + kk + seg * 4;
                float4 v = *(const float4*)xp;
                uint2 o; o.x = pk2(v.x, v.y); o.y = pk2(v.z, v.w);
                *(uint2*)&At[r * 40 + seg * 4] = o;
            }
        } else {
            #pragma unroll
            for (int i = 0; i < 2; i++) {           // A from carr (f16 direct)
                int idx = tid + i * 256;
                int r = idx >> 2, sg = idx & 3;
                int bc = mt * 128 + r;
                uint4 v = *(const uint4*)(carr + ((size_t)(h * 256 + bc)) * 128 + (kk - 256) + sg * 8);
                *(uint4*)&At[r * 40 + sg * 8] = v;
            }
        }
        #pragma unroll
        for (int i = 0; i < 2; i++) {               // B from aT
            int idx = tid + i * 256;
            int r = idx >> 2, sg = idx & 3;
            int t = nt * 128 + r;
            uint4 v = *(const uint4*)(aT + ((size_t)(h * 256 + t)) * 384 + kk + sg * 8);
            *(uint4*)&Bt[r * 40 + sg * 8] = v;
        }
        __syncthreads();
        f16x8 a[4], b[4];
        #pragma unroll
        for (int f = 0; f < 4; f++) {
            a[f] = *(const f16x8*)&At[(wm * 64 + f * 16 + lrow) * 40 + koff];
            b[f] = *(const f16x8*)&Bt[(wn * 64 + f * 16 + lrow) * 40 + koff];
        }
        #pragma unroll
        for (int fi = 0; fi < 4; fi++)
            #pragma unroll
            for (int fj = 0; fj < 4; fj++)
                acc[fi][fj] = __builtin_amdgcn_mfma_f32_16x16x32_f16(a[fi], b[fj], acc[fi][fj], 0, 0, 0);
    }
    #pragma unroll
    for (int fi = 0; fi < 4; fi++) {
        #pragma unroll
        for (int fj = 0; fj < 4; fj++) {
            int t = nt * 128 + wn * 64 + fj * 16 + lrow;
            #pragma unroll
            for (int rg = 0; rg < 4; rg++) {
                int bc = mt * 128 + wm * 64 + fi * 16 + quad * 4 + rg;
                yconv[(((size_t)((bc >> 5) * HCH + h)) << 13) + ((bc & 31) << 8) + t] = acc[fi][fj][rg];
            }
        }
    }
}

// branch-free GELU via A&S 7.1.25 erf approx (|err| <= 5e-4)
__device__ __forceinline__ float gelu_f(float y) {
    float z = fabsf(y) * 0.7071067811865476f;
    float p = fmaf(z, 0.078108f, 0.000972f);
    p = fmaf(z, p, 0.230389f);
    p = fmaf(z, p, 0.278393f);
    p = fmaf(z, p, 1.0f);
    float p2 = p * p;
    float p4 = p2 * p2;
    float er = 1.f - __builtin_amdgcn_rcpf(p4);
    float s  = copysignf(er, y);
    return 0.5f * y * (1.f + s);
}

// ---------------- K6: fused skip+GELU + 128x128 pointwise conv + BN stats ----------------
__global__ __launch_bounds__(256) void k_pointwise(const float* __restrict__ yconv,
                                                   const float* __restrict__ x,
                                                   const float* __restrict__ W,
                                                   const float* __restrict__ D,
                                                   float* __restrict__ z,
                                                   float* __restrict__ stats) {
    __shared__ float Wt[32][132];   // [h][o], padded (reused as stats scratch)
    __shared__ float Yt[32][68];    // [h][l], padded
    int b  = blockIdx.x >> 7;
    int l0 = (blockIdx.x & 127) << 6;
    int tid = threadIdx.x;
    int to4 = (tid & 31) << 2;      // owns o = to4..to4+3
    int tl  = tid >> 5;             // owns l = tl*8..tl*8+7
    float acc[4][8];
    #pragma unroll
    for (int a = 0; a < 4; a++)
        #pragma unroll
        for (int j = 0; j < 8; j++) acc[a][j] = 0.f;

    for (int ht = 0; ht < 4; ht++) {
        int hbase = ht * 32;
        __syncthreads();
        for (int i = tid; i < 4096; i += 256) {          // stage W tile
            int o = i >> 5, hh = i & 31;
            Wt[hh][o] = W[o * HCH + hbase + hh];
        }
        for (int i = tid; i < 2048; i += 256) {          // stage activated y tile
            int hh = i >> 6, l = i & 63;
            int hcur = hbase + hh;
            size_t gi = (size_t)(b * HCH + hcur) * LLEN + l0 + l;
            float yv = yconv[gi] + D[hcur] * x[gi];
            Yt[hh][l] = gelu_f(yv);
        }
        __syncthreads();
        #pragma unroll 8
        for (int hh = 0; hh < 32; hh++) {
            float4 wv = *(const float4*)&Wt[hh][to4];
            float4 ya = *(const float4*)&Yt[hh][tl * 8];
            float4 yb = *(const float4*)&Yt[hh][tl * 8 + 4];
            float wv4[4] = {wv.x, wv.y, wv.z, wv.w};
            float yv8[8] = {ya.x, ya.y, ya.z, ya.w, yb.x, yb.y, yb.z, yb.w};
            #pragma unroll
            for (int a = 0; a < 4; a++)
                #pragma unroll
                for (int j = 0; j < 8; j++)
                    acc[a][j] = fmaf(wv4[a], yv8[j], acc[a][j]);
        }
    }
    #pragma unroll
    for (int a = 0; a < 4; a++) {
        int o = to4 + a;
        size_t go = (size_t)(b * HCH + o) * LLEN + l0 + tl * 8;
        float4 s0 = {acc[a][0], acc[a][1], acc[a][2], acc[a][3]};
        float4 s1 = {acc[a][4], acc[a][5], acc[a][6], acc[a][7]};
        *(float4*)(z + go)     = s0;
        *(float4*)(z + go + 4) = s1;
    }
    // ---- fused BN stats ----
    __syncthreads();
    float* Ls = &Wt[0][0];
    #pragma unroll
    for (int a = 0; a < 4; a++) {
        float s = 0.f, qq = 0.f;
        #pragma unroll
        for (int j = 0; j < 8; j++) { s += acc[a][j]; qq = fmaf(acc[a][j], acc[a][j], qq); }
        Ls[tl * 132 + to4 + a]        = s;
        Ls[1056 + tl * 132 + to4 + a] = qq;
    }
    __syncthreads();
    if (tid < HCH) {
        float s = 0.f, qq = 0.f;
        #pragma unroll
        for (int t = 0; t < 8; t++) { s += Ls[t * 132 + tid]; qq += Ls[1056 + t * 132 + tid]; }
        atomicAdd(&stats[tid], s);
        atomicAdd(&stats[HCH + tid], qq);
    }
}

// ---------------- K7: BN normalize + ELU + residual ----------------
__global__ __launch_bounds__(256) void k_final(const float* __restrict__ z,
                                               const float* __restrict__ x,
                                               const float* __restrict__ stats,
                                               const float* __restrict__ gamma,
                                               const float* __restrict__ beta,
                                               float* __restrict__ out) {
    size_t i4 = (size_t)blockIdx.x * 256 + threadIdx.x;
    if (i4 >= (size_t)BB * HCH * LLEN / 4) return;
    size_t flat = i4 * 4;
    int o = (int)((flat / LLEN) & (HCH - 1));
    const float inv_cnt = 1.f / (float)(BB * LLEN);
    float m   = stats[o] * inv_cnt;
    float var = stats[HCH + o] * inv_cnt - m * m;
    float rs  = rsqrtf(var + 1e-5f);
    float ga  = gamma[o] * rs;
    float bt  = beta[o] - m * ga;
    float4 zv = ((const float4*)z)[i4];
    float4 xv = ((const float4*)x)[i4];
    float4 r;
    { float t = fmaf(zv.x, ga, bt); float e = t > 0.f ? t : (__expf(t) - 1.f); r.x = e + xv.x; }
    { float t = fmaf(zv.y, ga, bt); float e = t > 0.f ? t : (__expf(t) - 1.f); r.y = e + xv.y; }
    { float t = fmaf(zv.z, ga, bt); float e = t > 0.f ? t : (__expf(t) - 1.f); r.z = e + xv.z; }
    { float t = fmaf(zv.w, ga, bt); float e = t > 0.f ? t : (__expf(t) - 1.f); r.w = e + xv.w; }
    ((float4*)out)[i4] = r;
}

extern "C" void kernel_launch(void* const* d_in, const int* in_sizes, int n_in,
                              void* d_out, int out_size, void* d_ws, size_t ws_size,
                              hipStream_t stream) {
    const float* x     = (const float*)d_in[0];
    const float* C_re  = (const float*)d_in[1];
    const float* C_im  = (const float*)d_in[2];
    const float* logA  = (const float*)d_in[3];
    const float* Aim   = (const float*)d_in[4];
    const float* logdt = (const float*)d_in[5];
    const float* D     = (const float*)d_in[6];
    const float* W     = (const float*)d_in[7];
    const float* gamma = (const float*)d_in[8];
    const float* beta  = (const float*)d_in[9];

    float* ws = (float*)d_ws;
    // Region 0 (floats [0 .. 8388608)): yconv (written by k_conv_g);
    //   before that, hosts eT (2,097,152 f) + S_end (4,194,304 f) — both dead by then.
    float*     yconv = ws;
    _Float16*  eT    = (_Float16*)ws;                       // 4,194,304 halves
    float*     S_end = ws + 2097152;                        // 4,194,304 floats
    // Region 1 (floats [8388608 .. 16777216)): zbuf (k_pointwise output);
    //   before that, hosts aT (12,582,912 halves = 6,291,456 f) — dead by then.
    float*     zbuf  = ws + 8388608;
    _Float16*  aT    = (_Float16*)zbuf;
    // Region 2: carr (f16) + P + stats
    _Float16*  carr  = (_Float16*)(ws + 16777216);          // 4,194,304 halves
    float*     P     = ws + 16777216 + 2097152;
    float*     stats = P + 8 * 4096;
    float*     out   = (float*)d_out;

    k_setup    <<<16,   256, 0, stream>>>(C_re, C_im, logA, Aim, logdt, P, stats);
    k_prep     <<<128,  256, 0, stream>>>(P, aT, eT);
    k_states_g <<<256,  256, 0, stream>>>(x, eT, S_end);
    k_carries  <<<256,  256, 0, stream>>>(S_end, P, carr);
    k_conv_g   <<<512,  256, 0, stream>>>(x, aT, carr, yconv);
    k_pointwise<<<1024, 256, 0, stream>>>(yconv, x, W, D, zbuf, stats);
    k_final    <<<8192, 256, 0, stream>>>(zbuf, x, stats, gamma, beta, out);
}

// Round 7
// 212.443 us; speedup vs baseline: 3.5546x; 1.1218x over previous
//
#include <hip/hip_runtime.h>
#include <math.h>

#define HCH   128
#define NMODE 32
#define BB    8
#define LLEN  8192
#define LC    256
#define CCH   (LLEN / LC)      // 32 chunks per row
#define ROWS  (BB * HCH)       // 1024

typedef unsigned int uint;
typedef _Float16 f16x8 __attribute__((ext_vector_type(8)));
typedef float    f32x4 __attribute__((ext_vector_type(4)));

static __device__ __forceinline__ uint pk2(float a, float b) {
    union { _Float16 h[2]; uint u; } v;
    v.h[0] = (_Float16)a; v.h[1] = (_Float16)b;
    return v.u;
}

// w^e by fixed 8-step binary exponentiation (e in [0,255])
static __device__ __forceinline__ void cpow8(float wr, float wi, int e, float& pr, float& pi) {
    pr = 1.f; pi = 0.f;
    float br = wr, bi = wi;
    #pragma unroll
    for (int k = 0; k < 8; k++) {
        if (e & (1 << k)) { float t = pr * br - pi * bi; pi = pr * bi + pi * br; pr = t; }
        float t2 = br * br - bi * bi; bi = 2.f * br * bi; br = t2;
    }
}

// branch-free GELU via A&S 7.1.25 erf approx (|err| <= 5e-4)
__device__ __forceinline__ float gelu_f(float y) {
    float z = fabsf(y) * 0.7071067811865476f;
    float p = fmaf(z, 0.078108f, 0.000972f);
    p = fmaf(z, p, 0.230389f);
    p = fmaf(z, p, 0.278393f);
    p = fmaf(z, p, 1.0f);
    float p2 = p * p;
    float p4 = p2 * p2;
    float er = 1.f - __builtin_amdgcn_rcpf(p4);
    float s  = copysignf(er, y);
    return 0.5f * y * (1.f + s);
}

// VALU-pipe cross-lane add (DPP)
#define DPP_ADD(v, ctrl) { int _t = __builtin_amdgcn_update_dpp(0, __float_as_int(v), \
                             (ctrl), 0xF, 0xF, true); (v) += __int_as_float(_t); }

// ---------------- K1: per-h param compute + GEMM operand matrices (f16) ----------------
// aT[(h*256 + t)*384 + k]: k<256 Toeplitz M[t][s]; k=256+2n H0 coeffs; k=320+2n G1 coeffs.
// eT[(h*128 + srow)*256 + s]: srow=2n Re(w^{255-s}), 2n+1 Im; 64+2n Re(w^s), 65+2n Im.
// Also writes Pw (wL for carries) and zeroes stats (block 0).
__global__ __launch_bounds__(256) void k_prep(const float* __restrict__ C_re,
                                              const float* __restrict__ C_im,
                                              const float* __restrict__ logA,
                                              const float* __restrict__ Aim,
                                              const float* __restrict__ logdt,
                                              _Float16* __restrict__ aT,
                                              _Float16* __restrict__ eT,
                                              float* __restrict__ Pw,
                                              float* __restrict__ stats) {
    __shared__ float wrL[32], wiL[32];
    __shared__ float G0r[32], G0i[32], G1r[32], G1i[32], H0r[32], H0i[32];
    __shared__ float k0L[256], k1L[256];
    int tid = threadIdx.x;
    int h = blockIdx.x;
    if (blockIdx.x == 0) stats[tid] = 0.f;     // 256 entries
    if (tid < 32) {
        int n = tid, idx = h * 32 + n;
        float ar = expf(logA[idx]);
        float ai = Aim[idx];
        float dt = expf(logdt[h]);
        float dre = -ar * dt, dim = ai * dt;
        float er = expf(dre);
        float wr = er * cosf(dim), wi = er * sinf(dim);
        wrL[n] = wr; wiL[n] = wi;
        float eL = expf(dre * 256.f);
        Pw[idx]        = eL * cosf(dim * 256.f);
        Pw[4096 + idx] = eL * sinf(dim * 256.f);
        float den  = ar * ar + ai * ai;
        float numr = -(wr - 1.f) * ar + wi * ai;
        float numi = -wi * ar - (wr - 1.f) * ai;
        float Kr = numr / den, Ki = numi / den;
        float c0r = C_re[idx],        c0i = C_im[idx];
        float c1r = C_re[4096 + idx], c1i = C_im[4096 + idx];
        float g0r = 2.f * (c0r * Kr - c0i * Ki), g0i = 2.f * (c0r * Ki + c0i * Kr);
        G0r[n] = g0r; G0i[n] = g0i;
        G1r[n] = 2.f * (c1r * Kr - c1i * Ki);
        G1i[n] = 2.f * (c1r * Ki + c1i * Kr);
        H0r[n] = g0r * wr - g0i * wi;
        H0i[n] = g0r * wi + g0i * wr;
    }
    __syncthreads();
    // k0[tau] = Re(sum G0 w^tau); k1[tau] = Re(sum G1 w^tau)
    {
        int tau = tid;
        float s0 = 0.f, s1 = 0.f;
        for (int n = 0; n < 32; n++) {
            float pr, pi2; cpow8(wrL[n], wiL[n], tau, pr, pi2);
            s0 += G0r[n] * pr - G0i[n] * pi2;
            s1 += G1r[n] * pr - G1i[n] * pi2;
        }
        k0L[tau] = s0; k1L[tau] = s1;
    }
    __syncthreads();
    // Toeplitz part: 256 t x 256 s
    for (int idx = tid; idx < 256 * 128; idx += 256) {
        int t  = idx >> 7;
        int sp = (idx & 127) << 1;
        float v0 = (sp     <= t) ? k0L[t - sp]     : k1L[sp - t - 1];
        float v1 = (sp + 1 <= t) ? k0L[t - sp - 1] : k1L[sp - t];
        *(uint*)&aT[((size_t)(h * 256 + t)) * 384 + sp] = pk2(v0, v1);
    }
    // carry-coefficient columns
    {
        int t = tid;
        size_t rb = ((size_t)(h * 256 + t)) * 384;
        for (int n = 0; n < 32; n++) {
            float wtr, wti, wur, wui;
            cpow8(wrL[n], wiL[n], t, wtr, wti);
            cpow8(wrL[n], wiL[n], 255 - t, wur, wui);
            float v0r = H0r[n] * wtr - H0i[n] * wti;
            float v0i = -(H0r[n] * wti + H0i[n] * wtr);
            float v1r = G1r[n] * wur - G1i[n] * wui;
            float v1i = -(G1r[n] * wui + G1i[n] * wur);
            *(uint*)&aT[rb + 256 + 2 * n] = pk2(v0r, v0i);
            *(uint*)&aT[rb + 320 + 2 * n] = pk2(v1r, v1i);
        }
    }
    // eT (state-gather Vandermonde)
    for (int idx = tid; idx < 32 * 256; idx += 256) {
        int n = idx >> 8, s = idx & 255;
        float ar, ai2, br, bi2;
        cpow8(wrL[n], wiL[n], 255 - s, ar, ai2);
        cpow8(wrL[n], wiL[n], s, br, bi2);
        size_t base = (size_t)h * 128 * 256;
        eT[base + (size_t)(2 * n) * 256 + s]      = (_Float16)ar;
        eT[base + (size_t)(2 * n + 1) * 256 + s]  = (_Float16)ai2;
        eT[base + (size_t)(64 + 2 * n) * 256 + s] = (_Float16)br;
        eT[base + (size_t)(65 + 2 * n) * 256 + s] = (_Float16)bi2;
    }
}

// ---------------- K2: chunk-end states via MFMA GEMM ----------------
__global__ __launch_bounds__(256, 2) void k_states_g(const float* __restrict__ x,
                                                     const _Float16* __restrict__ eT,
                                                     float* __restrict__ S_end) {
    __shared__ _Float16 At[128 * 40];
    __shared__ _Float16 Bt[128 * 40];
    int tid = threadIdx.x;
    int bid = blockIdx.x;
    int h = bid >> 1, mt = bid & 1;
    int wave = tid >> 6, lane = tid & 63;
    int wm = wave >> 1, wn = wave & 1;
    int lrow = lane & 15, quad = lane >> 4;
    int koff = quad * 8;
    f32x4 acc[4][4];
    #pragma unroll
    for (int a = 0; a < 4; a++)
        #pragma unroll
        for (int b = 0; b < 4; b++) acc[a][b] = (f32x4){0.f, 0.f, 0.f, 0.f};

    for (int kk = 0; kk < 256; kk += 32) {
        __syncthreads();
        #pragma unroll
        for (int i = 0; i < 4; i++) {               // A: x rows (fp32 -> f16)
            int idx = tid + i * 256;
            int r = idx >> 3, seg = idx & 7;
            int bc = mt * 128 + r;
            const float* xp = x + (((size_t)((bc >> 5) * HCH + h)) << 13) + ((bc & 31) << 8) + kk + seg * 4;
            float4 v = *(const float4*)xp;
            uint2 o; o.x = pk2(v.x, v.y); o.y = pk2(v.z, v.w);
            *(uint2*)&At[r * 40 + seg * 4] = o;
        }
        #pragma unroll
        for (int i = 0; i < 2; i++) {               // B: eT rows (f16 direct)
            int idx = tid + i * 256;
            int r = idx >> 2, sg = idx & 3;
            uint4 v = *(const uint4*)(eT + ((size_t)(h * 128 + r)) * 256 + kk + sg * 8);
            *(uint4*)&Bt[r * 40 + sg * 8] = v;
        }
        __syncthreads();
        f16x8 a[4], b[4];
        #pragma unroll
        for (int f = 0; f < 4; f++) {
            a[f] = *(const f16x8*)&At[(wm * 64 + f * 16 + lrow) * 40 + koff];
            b[f] = *(const f16x8*)&Bt[(wn * 64 + f * 16 + lrow) * 40 + koff];
        }
        #pragma unroll
        for (int fi = 0; fi < 4; fi++)
            #pragma unroll
            for (int fj = 0; fj < 4; fj++)
                acc[fi][fj] = __builtin_amdgcn_mfma_f32_16x16x32_f16(a[fi], b[fj], acc[fi][fj], 0, 0, 0);
    }
    #pragma unroll
    for (int fi = 0; fi < 4; fi++) {
        #pragma unroll
        for (int fj = 0; fj < 4; fj++) {
            int srow = wn * 64 + fj * 16 + lrow;
            #pragma unroll
            for (int rg = 0; rg < 4; rg++) {
                int bc = mt * 128 + wm * 64 + fi * 16 + quad * 4 + rg;
                S_end[((size_t)(h * 256 + bc)) * 128 + srow] = acc[fi][fj][rg];
            }
        }
    }
}

// ---------------- K3: carry propagation (fp32) -> f16 carry columns ----------------
__global__ void k_carries(const float* __restrict__ S_end, const float* __restrict__ Pw,
                          _Float16* __restrict__ carr) {
    int i = blockIdx.x * 256 + threadIdx.x;   // over ROWS*2*NMODE = 65536
    int n = i & 31; int d = (i >> 5) & 1; int row = i >> 6;  // row = b*128 + h
    int h = row & (HCH - 1), b = row >> 7;
    int pi = h * NMODE + n;
    float wLr = Pw[pi], wLi = Pw[4096 + pi];
    int srow = d * 64 + 2 * n;
    float cr = 0.f, ci = 0.f;
    if (d == 0) {
        for (int c = 0; c < CCH; c++) {           // carry entering chunk c
            size_t base = ((size_t)(h * 256 + b * 32 + c)) * 128 + srow;
            carr[base] = (_Float16)cr; carr[base + 1] = (_Float16)ci;
            float sr = S_end[base], si = S_end[base + 1];
            float nr = fmaf(wLr, cr, -wLi * ci) + sr;
            float ni = fmaf(wLi, cr,  wLr * ci) + si;
            cr = nr; ci = ni;
        }
    } else {
        for (int c = CCH - 1; c >= 0; c--) {      // T at local t=255 of chunk c
            size_t base = ((size_t)(h * 256 + b * 32 + c)) * 128 + srow;
            carr[base] = (_Float16)cr; carr[base + 1] = (_Float16)ci;
            float sr = S_end[base], si = S_end[base + 1];
            float nr = fmaf(wLr, cr, -wLi * ci) + sr;
            float ni = fmaf(wLi, cr,  wLr * ci) + si;
            cr = nr; ci = ni;
        }
    }
}

// ---------------- K4: bidirectional conv GEMM (K=384) + fused skip+GELU -> f16 Yg ----------------
__global__ __launch_bounds__(256, 2) void k_conv_g(const float* __restrict__ x,
                                                   const _Float16* __restrict__ aT,
                                                   const _Float16* __restrict__ carr,
                                                   const float* __restrict__ D,
                                                   _Float16* __restrict__ Yg) {
    __shared__ _Float16 At[128 * 40];
    __shared__ _Float16 Bt[128 * 40];
    int tid = threadIdx.x;
    int bid = blockIdx.x;
    int h = bid >> 2, mt = (bid >> 1) & 1, nt = bid & 1;
    int wave = tid >> 6, lane = tid & 63;
    int wm = wave >> 1, wn = wave & 1;
    int lrow = lane & 15, quad = lane >> 4;
    int koff = quad * 8;
    f32x4 acc[4][4];
    #pragma unroll
    for (int a = 0; a < 4; a++)
        #pragma unroll
        for (int b = 0; b < 4; b++) acc[a][b] = (f32x4){0.f, 0.f, 0.f, 0.f};

    for (int kk = 0; kk < 384; kk += 32) {
        __syncthreads();
        if (kk < 256) {
            #pragma unroll
            for (int i = 0; i < 4; i++) {           // A from x (fp32 -> f16)
                int idx = tid + i * 256;
                int r = idx >> 3, seg = idx & 7;
                int bc = mt * 128 + r;
                const float* xp = x + (((size_t)((bc >> 5) * HCH + h)) << 13) + ((bc & 31) << 8) + kk + seg * 4;
                float4 v = *(const float4*)xp;
                uint2 o; o.x = pk2(v.x, v.y); o.y = pk2(v.z, v.w);
                *(uint2*)&At[r * 40 + seg * 4] = o;
            }
        } else {
            #pragma unroll
            for (int i = 0; i < 2; i++) {           // A from carr (f16 direct)
                int idx = tid + i * 256;
                int r = idx >> 2, sg = idx & 3;
                int bc = mt * 128 + r;
                uint4 v = *(const uint4*)(carr + ((size_t)(h * 256 + bc)) * 128 + (kk - 256) + sg * 8);
                *(uint4*)&At[r * 40 + sg * 8] = v;
            }
        }
        #pragma unroll
        for (int i = 0; i < 2; i++) {               // B from aT
            int idx = tid + i * 256;
            int r = idx >> 2, sg = idx & 3;
            int t = nt * 128 + r;
            uint4 v = *(const uint4*)(aT + ((size_t)(h * 256 + t)) * 384 + kk + sg * 8);
            *(uint4*)&Bt[r * 40 + sg * 8] = v;
        }
        __syncthreads();
        f16x8 a[4], b[4];
        #pragma unroll
        for (int f = 0; f < 4; f++) {
            a[f] = *(const f16x8*)&At[(wm * 64 + f * 16 + lrow) * 40 + koff];
            b[f] = *(const f16x8*)&Bt[(wn * 64 + f * 16 + lrow) * 40 + koff];
        }
        #pragma unroll
        for (int fi = 0; fi < 4; fi++)
            #pragma unroll
            for (int fj = 0; fj < 4; fj++)
                acc[fi][fj] = __builtin_amdgcn_mfma_f32_16x16x32_f16(a[fi], b[fj], acc[fi][fj], 0, 0, 0);
    }
    // fused epilogue: skip + GELU -> f16 store
    float Dh = D[h];
    #pragma unroll
    for (int fi = 0; fi < 4; fi++) {
        #pragma unroll
        for (int fj = 0; fj < 4; fj++) {
            int t = nt * 128 + wn * 64 + fj * 16 + lrow;
            #pragma unroll
            for (int rg = 0; rg < 4; rg++) {
                int bc = mt * 128 + wm * 64 + fi * 16 + quad * 4 + rg;
                size_t base = (((size_t)((bc >> 5) * HCH + h)) << 13) + ((bc & 31) << 8) + t;
                float xv = x[base];
                float yv = acc[fi][fj][rg] + Dh * xv;
                Yg[base] = (_Float16)gelu_f(yv);
            }
        }
    }
}

// ---------------- K5: pointwise conv as MFMA GEMM + fused BN stats ----------------
// z[b][o][l] = sum_h W[o][h] * Yg[b][h][l];  M=o(128), N=l-tile(128), K=h(128)
__global__ __launch_bounds__(256, 2) void k_pointwise(const _Float16* __restrict__ Yg,
                                                      const float* __restrict__ W,
                                                      float* __restrict__ z,
                                                      float* __restrict__ stats) {
    __shared__ _Float16 Wt[128 * 40];
    __shared__ _Float16 Yt[128 * 40];
    int tid = threadIdx.x;
    int b  = blockIdx.x >> 6;
    int l0 = (blockIdx.x & 63) << 7;
    int wave = tid >> 6, lane = tid & 63;
    int wm = wave >> 1, wn = wave & 1;
    int lrow = lane & 15, quad = lane >> 4;
    int koff = quad * 8;
    f32x4 acc[4][4];
    #pragma unroll
    for (int a = 0; a < 4; a++)
        #pragma unroll
        for (int c = 0; c < 4; c++) acc[a][c] = (f32x4){0.f, 0.f, 0.f, 0.f};

    for (int kk = 0; kk < 128; kk += 32) {
        __syncthreads();
        #pragma unroll
        for (int i = 0; i < 4; i++) {               // Wt: W fp32 -> f16, rows o
            int idx = tid + i * 256;
            int r = idx >> 3, seg = idx & 7;
            float4 v = *(const float4*)(W + r * HCH + kk + seg * 4);
            uint2 o2; o2.x = pk2(v.x, v.y); o2.y = pk2(v.z, v.w);
            *(uint2*)&Wt[r * 40 + seg * 4] = o2;
        }
        #pragma unroll
        for (int i = 0; i < 2; i++) {               // Yt transposed: [l][h]
            int idx = tid + i * 256;
            int hh = idx & 31, lg = idx >> 5;       // lanes vary hh -> 2-4 way LDS aliasing only
            uint4 v = *(const uint4*)(Yg + (((size_t)(b * HCH + kk + hh)) << 13) + l0 + lg * 8);
            const _Float16* hv = (const _Float16*)&v;
            #pragma unroll
            for (int j = 0; j < 8; j++)
                Yt[(lg * 8 + j) * 40 + hh] = hv[j];
        }
        __syncthreads();
        f16x8 a[4], bf[4];
        #pragma unroll
        for (int f = 0; f < 4; f++) {
            a[f]  = *(const f16x8*)&Wt[(wm * 64 + f * 16 + lrow) * 40 + koff];
            bf[f] = *(const f16x8*)&Yt[(wn * 64 + f * 16 + lrow) * 40 + koff];
        }
        #pragma unroll
        for (int fi = 0; fi < 4; fi++)
            #pragma unroll
            for (int fj = 0; fj < 4; fj++)
                acc[fi][fj] = __builtin_amdgcn_mfma_f32_16x16x32_f16(a[fi], bf[fj], acc[fi][fj], 0, 0, 0);
    }
    // store z
    #pragma unroll
    for (int fi = 0; fi < 4; fi++) {
        #pragma unroll
        for (int fj = 0; fj < 4; fj++) {
            int l = l0 + wn * 64 + fj * 16 + lrow;
            #pragma unroll
            for (int rg = 0; rg < 4; rg++) {
                int o = wm * 64 + fi * 16 + quad * 4 + rg;
                z[(((size_t)(b * HCH + o)) << 13) + l] = acc[fi][fj][rg];
            }
        }
    }
    // fused BN stats: 16-lane DPP butterfly (o is constant across lrow), LDS, atomics
    __syncthreads();
    float* Ls = (float*)Wt;   // 512 floats
    #pragma unroll
    for (int fi = 0; fi < 4; fi++) {
        #pragma unroll
        for (int rg = 0; rg < 4; rg++) {
            float s = 0.f, q = 0.f;
            #pragma unroll
            for (int fj = 0; fj < 4; fj++) {
                float v = acc[fi][fj][rg];
                s += v; q = fmaf(v, v, q);
            }
            DPP_ADD(s, 0xB1); DPP_ADD(s, 0x4E); DPP_ADD(s, 0x141); DPP_ADD(s, 0x140);
            DPP_ADD(q, 0xB1); DPP_ADD(q, 0x4E); DPP_ADD(q, 0x141); DPP_ADD(q, 0x140);
            if (lrow == 0) {
                int olo = fi * 16 + quad * 4 + rg;
                Ls[wave * 64 + olo]       = s;
                Ls[256 + wave * 64 + olo] = q;
            }
        }
    }
    __syncthreads();
    if (tid < HCH) {
        int wmn = tid >> 6;
        int olo = tid & 63;
        float s = Ls[(wmn * 2) * 64 + olo] + Ls[(wmn * 2 + 1) * 64 + olo];
        float q = Ls[256 + (wmn * 2) * 64 + olo] + Ls[256 + (wmn * 2 + 1) * 64 + olo];
        atomicAdd(&stats[tid], s);
        atomicAdd(&stats[HCH + tid], q);
    }
}

// ---------------- K6: BN normalize + ELU + residual ----------------
__global__ __launch_bounds__(256) void k_final(const float* __restrict__ z,
                                               const float* __restrict__ x,
                                               const float* __restrict__ stats,
                                               const float* __restrict__ gamma,
                                               const float* __restrict__ beta,
                                               float* __restrict__ out) {
    size_t i4 = (size_t)blockIdx.x * 256 + threadIdx.x;
    if (i4 >= (size_t)BB * HCH * LLEN / 4) return;
    size_t flat = i4 * 4;
    int o = (int)((flat / LLEN) & (HCH - 1));
    const float inv_cnt = 1.f / (float)(BB * LLEN);
    float m   = stats[o] * inv_cnt;
    float var = stats[HCH + o] * inv_cnt - m * m;
    float rs  = rsqrtf(var + 1e-5f);
    float ga  = gamma[o] * rs;
    float bt  = beta[o] - m * ga;
    float4 zv = ((const float4*)z)[i4];
    float4 xv = ((const float4*)x)[i4];
    float4 r;
    { float t = fmaf(zv.x, ga, bt); float e = t > 0.f ? t : (__expf(t) - 1.f); r.x = e + xv.x; }
    { float t = fmaf(zv.y, ga, bt); float e = t > 0.f ? t : (__expf(t) - 1.f); r.y = e + xv.y; }
    { float t = fmaf(zv.z, ga, bt); float e = t > 0.f ? t : (__expf(t) - 1.f); r.z = e + xv.z; }
    { float t = fmaf(zv.w, ga, bt); float e = t > 0.f ? t : (__expf(t) - 1.f); r.w = e + xv.w; }
    ((float4*)out)[i4] = r;
}

extern "C" void kernel_launch(void* const* d_in, const int* in_sizes, int n_in,
                              void* d_out, int out_size, void* d_ws, size_t ws_size,
                              hipStream_t stream) {
    const float* x     = (const float*)d_in[0];
    const float* C_re  = (const float*)d_in[1];
    const float* C_im  = (const float*)d_in[2];
    const float* logA  = (const float*)d_in[3];
    const float* Aim   = (const float*)d_in[4];
    const float* logdt = (const float*)d_in[5];
    const float* D     = (const float*)d_in[6];
    const float* W     = (const float*)d_in[7];
    const float* gamma = (const float*)d_in[8];
    const float* beta  = (const float*)d_in[9];

    float* ws = (float*)d_ws;
    // [0 .. 2097152): eT f16 (dead after k_states_g)
    // [2097152 .. 6291456): S_end f32 (dead after k_carries)
    // [0 .. 4194304): Yg f16 (written by k_conv_g, after eT/S_end are dead)
    _Float16* eT    = (_Float16*)ws;
    float*    S_end = ws + 2097152;
    _Float16* Yg    = (_Float16*)ws;
    // [8388608 .. 16777216): aT f16 (6.29M floats worth), then zbuf f32 (aT dead by then)
    float*    zbuf  = ws + 8388608;
    _Float16* aT    = (_Float16*)zbuf;
    // [16777216 ..): carr f16 + Pw + stats
    _Float16* carr  = (_Float16*)(ws + 16777216);
    float*    Pw    = ws + 16777216 + 2097152;
    float*    stats = Pw + 8192;
    float*    out   = (float*)d_out;

    k_prep     <<<128,  256, 0, stream>>>(C_re, C_im, logA, Aim, logdt, aT, eT, Pw, stats);
    k_states_g <<<256,  256, 0, stream>>>(x, eT, S_end);
    k_carries  <<<256,  256, 0, stream>>>(S_end, Pw, carr);
    k_conv_g   <<<512,  256, 0, stream>>>(x, aT, carr, D, Yg);
    k_pointwise<<<512,  256, 0, stream>>>(Yg, W, zbuf, stats);
    k_final    <<<8192, 256, 0, stream>>>(zbuf, x, stats, gamma, beta, out);
}